// Round 4
// baseline (5930.904 us; speedup 1.0000x reference)
//
#include <hip/hip_runtime.h>

#define I_SZ 256
#define H_SZ 512
#define O_SZ 256
#define B_SZ 4096
#define S_SZ 50
#define T_SZ 20
#define G4H  2048
#define BH   ((size_t)B_SZ * H_SZ)
#define NB   512                 // persistent grid: 2 blocks/CU x 256 CU
#define NSTEP (S_SZ + T_SZ)

#define PAD 72   // k_fc only

typedef _Float16 half8 __attribute__((ext_vector_type(8)));
typedef float f32x4 __attribute__((ext_vector_type(4)));

__device__ __forceinline__ float sigm(float x) {
    return 1.0f / (1.0f + __expf(-x));
}
__device__ __forceinline__ float tanh_fast(float x) {
    float e = __expf(2.0f * x);
    return 1.0f - 2.0f / (e + 1.0f);
}

// async global->LDS, 16B per lane, linear LDS dest (wave-uniform base + lane*16)
#define GLDS(gp, lp) __builtin_amdgcn_global_load_lds(                      \
    (const __attribute__((address_space(1))) void*)(gp),                    \
    (__attribute__((address_space(3))) void*)(lp), 16, 0, 0)

// ---------------- one-time prep kernels ----------------
__global__ void k_zero1(unsigned* p) { *p = 0u; }

__global__ void k_cvt(const float* __restrict__ src, _Float16* __restrict__ dst, int n) {
    int i = blockIdx.x * blockDim.x + threadIdx.x;
    if (i < n) dst[i] = (_Float16)src[i];
}

__global__ void k_bias_combine(const float* __restrict__ a, const float* __restrict__ b,
                               float* __restrict__ dst, int n) {
    int i = blockIdx.x * blockDim.x + threadIdx.x;
    if (i < n) dst[i] = a[i] + b[i];
}

// x [B][S][I] fp32 -> xT [S][B][I] fp16
__global__ __launch_bounds__(256) void k_cvt_x(const float* __restrict__ x,
                                               _Float16* __restrict__ xT) {
    size_t idx = ((size_t)blockIdx.x * 256 + threadIdx.x) * 8;
    int i = (int)(idx & 255);
    int s = (int)((idx >> 8) % S_SZ);
    size_t b = idx / (256 * S_SZ);
    float4 v0 = *(const float4*)(x + idx);
    float4 v1 = *(const float4*)(x + idx + 4);
    half8 hv;
    hv[0] = (_Float16)v0.x; hv[1] = (_Float16)v0.y;
    hv[2] = (_Float16)v0.z; hv[3] = (_Float16)v0.w;
    hv[4] = (_Float16)v1.x; hv[5] = (_Float16)v1.y;
    hv[6] = (_Float16)v1.z; hv[7] = (_Float16)v1.w;
    *(half8*)(xT + (((size_t)s * B_SZ + b) * I_SZ + i)) = hv;
}

// Wenc[r][0:256]=eWih[r], [256:768]=eWhh[r]  (fp16)
__global__ void k_wenc(const float* __restrict__ eWih, const float* __restrict__ eWhh,
                       _Float16* __restrict__ Wenc) {
    int idx = blockIdx.x * blockDim.x + threadIdx.x;
    int r = idx / 768, col = idx % 768;
    float v = (col < 256) ? eWih[(size_t)r * 256 + col] : eWhh[(size_t)r * 512 + col - 256];
    Wenc[idx] = (_Float16)v;
}

// Wd[r,k] = dWhh[r,k] + sum_o dWih[r,o] * fcW[o,k]
__global__ __launch_bounds__(256) void k_wd(
    const float* __restrict__ dWhh, const float* __restrict__ dWih,
    const float* __restrict__ fcW, _Float16* __restrict__ Wd)
{
    __shared__ float sA[8][256];
    const int tid = threadIdx.x;
    const int r0 = blockIdx.x * 8;
    {
        int linear = tid * 8;
        int row = linear >> 8, col = linear & 255;
        const float4* p = (const float4*)(dWih + (size_t)(r0 + row) * 256 + col);
        float4 v0 = p[0], v1 = p[1];
        *(float4*)&sA[row][col]     = v0;
        *(float4*)&sA[row][col + 4] = v1;
    }
    __syncthreads();
    float acc[8][2] = {};
    const int k = tid;
    for (int i = 0; i < 256; ++i) {
        float w0 = fcW[(size_t)i * 512 + k];
        float w1 = fcW[(size_t)i * 512 + k + 256];
        #pragma unroll
        for (int rr = 0; rr < 8; ++rr) {
            float a = sA[rr][i];
            acc[rr][0] += a * w0;
            acc[rr][1] += a * w1;
        }
    }
    #pragma unroll
    for (int rr = 0; rr < 8; ++rr) {
        size_t base = (size_t)(r0 + rr) * 512;
        Wd[base + k]       = (_Float16)(dWhh[base + k]       + acc[rr][0]);
        Wd[base + k + 256] = (_Float16)(dWhh[base + k + 256] + acc[rr][1]);
    }
}

// bd[r] = db[r] + sum_o dWih[r,o] * fcb[o]
__global__ __launch_bounds__(256) void k_bd(
    const float* __restrict__ dWih, const float* __restrict__ fcb,
    const float* __restrict__ db, float* __restrict__ bd)
{
    __shared__ float sf[256];
    const int tid = threadIdx.x;
    sf[tid] = fcb[tid];
    __syncthreads();
    int r = blockIdx.x * 256 + tid;
    float acc = db[r];
    const float* row = dWih + (size_t)r * 256;
    for (int o = 0; o < 256; o += 4) {
        float4 v = *(const float4*)(row + o);
        acc += v.x * sf[o] + v.y * sf[o + 1] + v.z * sf[o + 2] + v.w * sf[o + 3];
    }
    bd[r] = acc;
}

// ---------------- persistent whole-recurrence kernel ----------------
// 512 blocks x 256 thr, exactly 2 blocks/CU (64KB LDS). Each block owns a fixed
// (128-batch x 32-j x 4-gate) output tile for all 70 steps; c stays in VGPRs.
// Steps separated by a monotonic device-scope atomic grid barrier.
__global__ __launch_bounds__(256, 2) void k_lstm_all(
    const _Float16* __restrict__ xT,     // [S][B][256] fp16
    const _Float16* __restrict__ Wenc,   // [2048][768]
    const _Float16* __restrict__ dWhh_h, // [2048][512]
    const _Float16* __restrict__ Wd,     // [2048][512]
    const float* __restrict__ eb, const float* __restrict__ db,
    const float* __restrict__ bd,
    _Float16* __restrict__ h0buf, _Float16* __restrict__ h1buf,
    _Float16* __restrict__ hseq,         // [T+1][B][512]
    unsigned* __restrict__ bar)
{
    __shared__ _Float16 lds[2][2][128 * 64];   // 64 KB

    const int tid = threadIdx.x;
    // XCD-swizzle: consecutive jb-sharing blocks land on one XCD (512 % 8 == 0)
    const int blk = (blockIdx.x & 7) * 64 + (blockIdx.x >> 3);
    const int mb = blk & 31, jb = blk >> 5;
    const int m0 = mb * 128, j0 = jb * 32;
    const int wv = tid >> 6, lane = tid & 63, lrow = lane & 15, lk8 = (lane >> 4) * 8;
    const int wm = wv >> 1, wn = wv & 1;

    // staging geometry
    const int colb  = (lane & 7) * 16;
    const int scolh = (colb ^ (((lane >> 3) & 7) << 4)) >> 1;
    int rowq[4], growq[4];
    #pragma unroll
    for (int q = 0; q < 4; ++q) {
        int r = q * 32 + wv * 8 + (lane >> 3);
        rowq[q] = r;
        growq[q] = ((r >> 4) & 3) * H_SZ + j0 + (r >> 6) * 16 + (r & 15);
    }

    // preload the three bias variants for this thread's 4 gate-cols
    float ebj[4], dbj[4], bdj[4];
    #pragma unroll
    for (int nf = 0; nf < 4; ++nf) {
        int col = nf * H_SZ + j0 + wn * 16 + lrow;
        ebj[nf] = eb[col]; dbj[nf] = db[col]; bdj[nf] = bd[col];
    }

    float creg[4][4];   // persistent cell state: [mf][r]
    const int j = j0 + wn * 16 + lrow;

    for (int step = 0; step < NSTEP; ++step) {
        // ---- per-step routing (wave-uniform) ----
        const _Float16* xsrc; const _Float16* hin; const _Float16* W;
        _Float16* hout; int wstride, nx, niter;
        if (step < S_SZ) {
            xsrc = xT + (size_t)step * B_SZ * I_SZ;
            W = Wenc; wstride = 768; nx = 4;
            niter = (step == 0) ? 4 : 12;
            hin  = (step == 0) ? nullptr : ((step & 1) ? h0buf : h1buf);
            hout = (step == S_SZ - 1) ? hseq : ((step & 1) ? h1buf : h0buf);
        } else {
            int t = step - S_SZ;
            xsrc = nullptr; nx = 0; niter = 8; wstride = 512;
            W = (t == 0) ? dWhh_h : Wd;
            hin  = hseq + (size_t)t * BH;
            hout = hseq + (size_t)(t + 1) * BH;
        }

        auto stage = [&](int buf, int it) {
            const int koffW = it * 64;
            const _Float16* Ab; int astr, koffA;
            if (it < nx) { Ab = xsrc; astr = I_SZ; koffA = it * 64; }
            else         { Ab = hin;  astr = H_SZ; koffA = (it - nx) * 64; }
            #pragma unroll
            for (int q = 0; q < 4; ++q) {
                const _Float16* ga = Ab + (size_t)(m0 + rowq[q]) * astr + koffA + scolh;
                GLDS(ga, &lds[buf][0][(q * 256 + wv * 64) * 8]);
            }
            #pragma unroll
            for (int q = 0; q < 4; ++q) {
                const _Float16* gb = W + (size_t)growq[q] * wstride + koffW + scolh;
                GLDS(gb, &lds[buf][1][(q * 256 + wv * 64) * 8]);
            }
        };

        f32x4 acc[4][4];
        #pragma unroll
        for (int mf = 0; mf < 4; ++mf)
            #pragma unroll
            for (int nf = 0; nf < 4; ++nf) {
                f32x4 z = {0.f, 0.f, 0.f, 0.f};
                acc[mf][nf] = z;
            }

        auto compute = [&](int buf) {
            #pragma unroll
            for (int kc = 0; kc < 2; ++kc) {
                const int cb = (kc * 32 + lk8) * 2;
                const int sc = (cb ^ ((lrow & 7) << 4)) >> 1;
                half8 a[4], b[4];
                #pragma unroll
                for (int mf = 0; mf < 4; ++mf)
                    a[mf] = *(const half8*)&lds[buf][0][(wm * 64 + mf * 16 + lrow) * 64 + sc];
                #pragma unroll
                for (int nf = 0; nf < 4; ++nf)
                    b[nf] = *(const half8*)&lds[buf][1][(wn * 64 + nf * 16 + lrow) * 64 + sc];
                #pragma unroll
                for (int mf = 0; mf < 4; ++mf)
                    #pragma unroll
                    for (int nf = 0; nf < 4; ++nf)
                        acc[mf][nf] = __builtin_amdgcn_mfma_f32_16x16x32_f16(a[mf], b[nf], acc[mf][nf], 0, 0, 0);
            }
        };

        stage(0, 0);
        __syncthreads();
        int buf = 0;
        for (int it = 0; it < niter; ++it) {
            if (it + 1 < niter) stage(buf ^ 1, it + 1);
            compute(buf);
            __syncthreads();
            buf ^= 1;
        }

        // ---- epilogue ----
        float bj[4];
        #pragma unroll
        for (int nf = 0; nf < 4; ++nf)
            bj[nf] = (step < S_SZ) ? ebj[nf] : ((step == S_SZ) ? dbj[nf] : bdj[nf]);

        #pragma unroll
        for (int mf = 0; mf < 4; ++mf)
            #pragma unroll
            for (int r = 0; r < 4; ++r) {
                int m = m0 + wm * 64 + mf * 16 + (lane >> 4) * 4 + r;
                float gi = acc[mf][0][r] + bj[0];
                float gf = acc[mf][1][r] + bj[1];
                float gg = acc[mf][2][r] + bj[2];
                float go = acc[mf][3][r] + bj[3];
                float cold = (step == 0) ? 0.0f : creg[mf][r];
                float cn = sigm(gf) * cold + sigm(gi) * tanh_fast(gg);
                creg[mf][r] = cn;
                hout[(size_t)m * H_SZ + j] = (_Float16)(sigm(go) * tanh_fast(cn));
            }

        // ---- grid barrier (monotonic, device-scope) ----
        if (step != NSTEP - 1) {
            __syncthreads();
            if (tid == 0) {
                __threadfence();
                __hip_atomic_fetch_add(bar, 1u, __ATOMIC_RELEASE, __HIP_MEMORY_SCOPE_AGENT);
                unsigned target = (unsigned)(step + 1) * NB;
                while (__hip_atomic_fetch_add(bar, 0u, __ATOMIC_ACQUIRE, __HIP_MEMORY_SCOPE_AGENT) < target)
                    __builtin_amdgcn_s_sleep(2);
                __threadfence();
            }
            __syncthreads();
        }
    }
}

// ---------------- batched final FC over all decoder h's ----------------
__global__ __launch_bounds__(256) void k_fc(
    const _Float16* __restrict__ hseq1,  // [T][B][512]
    const _Float16* __restrict__ W,      // fcW fp16 [256][512]
    const float* __restrict__ bias,      // [256]
    float* __restrict__ out)
{
    __shared__ _Float16 Asm[128][PAD];
    __shared__ _Float16 Bsm[128][PAD];

    const int tid = threadIdx.x;
    const int m0 = blockIdx.x * 128;
    const int t  = blockIdx.y;
    const int n0 = blockIdx.z * 128;
    const int wv = tid >> 6, lane = tid & 63, lrow = lane & 15, lk = (lane >> 4) * 8;
    const int wm = wv >> 1, wn = wv & 1;

    f32x4 acc[4][4] = {};

    const int srow = tid >> 3, skc = (tid & 7) * 8;
    const _Float16* A = hseq1 + (size_t)t * BH;

    for (int k0 = 0; k0 < H_SZ; k0 += 64) {
        __syncthreads();
        #pragma unroll
        for (int q = 0; q < 4; ++q) {
            int r = srow + q * 32;
            *(half8*)&Asm[r][skc] = *(const half8*)(A + (size_t)(m0 + r) * H_SZ + k0 + skc);
        }
        #pragma unroll
        for (int q = 0; q < 4; ++q) {
            int rr = srow + q * 32;
            *(half8*)&Bsm[rr][skc] = *(const half8*)(W + (size_t)(n0 + rr) * H_SZ + k0 + skc);
        }
        __syncthreads();
        #pragma unroll
        for (int kc = 0; kc < 64; kc += 32) {
            half8 a[4], b[4];
            #pragma unroll
            for (int mf = 0; mf < 4; ++mf) a[mf] = *(const half8*)&Asm[wm * 64 + mf * 16 + lrow][kc + lk];
            #pragma unroll
            for (int nf = 0; nf < 4; ++nf) b[nf] = *(const half8*)&Bsm[wn * 64 + nf * 16 + lrow][kc + lk];
            #pragma unroll
            for (int mf = 0; mf < 4; ++mf)
                #pragma unroll
                for (int nf = 0; nf < 4; ++nf)
                    acc[mf][nf] = __builtin_amdgcn_mfma_f32_16x16x32_f16(a[mf], b[nf], acc[mf][nf], 0, 0, 0);
        }
    }

    #pragma unroll
    for (int mf = 0; mf < 4; ++mf)
        #pragma unroll
        for (int nf = 0; nf < 4; ++nf) {
            int o = n0 + wn * 64 + nf * 16 + lrow;
            float bv = bias[o];
            #pragma unroll
            for (int r = 0; r < 4; ++r) {
                int m = m0 + wm * 64 + mf * 16 + (lane >> 4) * 4 + r;
                out[(size_t)m * (T_SZ * O_SZ) + (size_t)t * O_SZ + o] = acc[mf][nf][r] + bv;
            }
        }
}

extern "C" void kernel_launch(void* const* d_in, const int* in_sizes, int n_in,
                              void* d_out, int out_size, void* d_ws, size_t ws_size,
                              hipStream_t stream) {
    (void)in_sizes; (void)n_in; (void)out_size; (void)ws_size;

    const float* x    = (const float*)d_in[0];
    const float* eWih = (const float*)d_in[1];
    const float* eWhh = (const float*)d_in[2];
    const float* ebih = (const float*)d_in[3];
    const float* ebhh = (const float*)d_in[4];
    const float* dWih = (const float*)d_in[5];
    const float* dWhh = (const float*)d_in[6];
    const float* dbih = (const float*)d_in[7];
    const float* dbhh = (const float*)d_in[8];
    const float* fcW  = (const float*)d_in[9];
    const float* fcb  = (const float*)d_in[10];
    float* out = (float*)d_out;
    char* ws = (char*)d_ws;

    size_t off = 0;
    auto alloc = [&](size_t bytes) -> void* {
        void* p = ws + off;
        off += (bytes + 255) & ~(size_t)255;
        return p;
    };
    _Float16* xT     = (_Float16*)alloc((size_t)S_SZ * B_SZ * I_SZ * 2);
    _Float16* Wenc   = (_Float16*)alloc((size_t)G4H * (I_SZ + H_SZ) * 2);
    _Float16* dWhh_h = (_Float16*)alloc((size_t)G4H * H_SZ * 2);
    _Float16* Wd     = (_Float16*)alloc((size_t)G4H * H_SZ * 2);
    _Float16* fcW_h  = (_Float16*)alloc((size_t)O_SZ * H_SZ * 2);
    float*    eb     = (float*)alloc(G4H * 4);
    float*    db     = (float*)alloc(G4H * 4);
    float*    bd     = (float*)alloc(G4H * 4);
    _Float16* h0     = (_Float16*)alloc(BH * 2);
    _Float16* h1     = (_Float16*)alloc(BH * 2);
    _Float16* hseq   = (_Float16*)alloc((size_t)(T_SZ + 1) * BH * 2);
    unsigned* bar    = (unsigned*)alloc(256);

    const int nWhh = G4H * H_SZ;
    const int nFc  = O_SZ * H_SZ;
    const size_t nX = (size_t)B_SZ * S_SZ * I_SZ;

    k_zero1<<<1, 1, 0, stream>>>(bar);
    k_cvt_x<<<(int)(nX / 8 / 256), 256, 0, stream>>>(x, xT);
    k_wenc<<<(G4H * 768) / 256, 256, 0, stream>>>(eWih, eWhh, Wenc);
    k_cvt<<<(nWhh + 255) / 256, 256, 0, stream>>>(dWhh, dWhh_h, nWhh);
    k_cvt<<<(nFc + 255) / 256, 256, 0, stream>>>(fcW, fcW_h, nFc);
    k_bias_combine<<<8, 256, 0, stream>>>(ebih, ebhh, eb, G4H);
    k_bias_combine<<<8, 256, 0, stream>>>(dbih, dbhh, db, G4H);
    k_wd<<<256, 256, 0, stream>>>(dWhh, dWih, fcW, Wd);
    k_bd<<<8, 256, 0, stream>>>(dWih, fcb, db, bd);

    k_lstm_all<<<NB, 256, 0, stream>>>(xT, Wenc, dWhh_h, Wd, eb, db, bd,
                                       h0, h1, hseq, bar);

    k_fc<<<dim3(B_SZ / 128, T_SZ, O_SZ / 128), 256, 0, stream>>>(
        hseq + BH, fcW_h, fcb, out);
}

// Round 5
// 3705.596 us; speedup vs baseline: 1.6005x; 1.6005x over previous
//
#include <hip/hip_runtime.h>

#define I_SZ 256
#define H_SZ 512
#define O_SZ 256
#define B_SZ 4096
#define S_SZ 50
#define T_SZ 20
#define G4H  2048
#define BH   ((size_t)B_SZ * H_SZ)
#define NB   512                 // persistent grid: 2 blocks/CU x 256 CU
#define NSTEP (S_SZ + T_SZ)

#define PAD 72   // k_fc only

typedef _Float16 half8 __attribute__((ext_vector_type(8)));
typedef float f32x4 __attribute__((ext_vector_type(4)));

__device__ __forceinline__ float sigm(float x) {
    return 1.0f / (1.0f + __expf(-x));
}
__device__ __forceinline__ float tanh_fast(float x) {
    float e = __expf(2.0f * x);
    return 1.0f - 2.0f / (e + 1.0f);
}

// async global->LDS, 16B per lane, linear LDS dest (wave-uniform base + lane*16)
#define GLDS(gp, lp) __builtin_amdgcn_global_load_lds(                      \
    (const __attribute__((address_space(1))) void*)(gp),                    \
    (__attribute__((address_space(3))) void*)(lp), 16, 0, 0)

// ---------------- one-time prep kernels ----------------
__global__ void k_zeroN(unsigned* p, int n) {
    int i = blockIdx.x * blockDim.x + threadIdx.x;
    if (i < n) p[i] = 0u;
}

__global__ void k_cvt(const float* __restrict__ src, _Float16* __restrict__ dst, int n) {
    int i = blockIdx.x * blockDim.x + threadIdx.x;
    if (i < n) dst[i] = (_Float16)src[i];
}

__global__ void k_bias_combine(const float* __restrict__ a, const float* __restrict__ b,
                               float* __restrict__ dst, int n) {
    int i = blockIdx.x * blockDim.x + threadIdx.x;
    if (i < n) dst[i] = a[i] + b[i];
}

// x [B][S][I] fp32 -> xT [S][B][I] fp16
__global__ __launch_bounds__(256) void k_cvt_x(const float* __restrict__ x,
                                               _Float16* __restrict__ xT) {
    size_t idx = ((size_t)blockIdx.x * 256 + threadIdx.x) * 8;
    int i = (int)(idx & 255);
    int s = (int)((idx >> 8) % S_SZ);
    size_t b = idx / (256 * S_SZ);
    float4 v0 = *(const float4*)(x + idx);
    float4 v1 = *(const float4*)(x + idx + 4);
    half8 hv;
    hv[0] = (_Float16)v0.x; hv[1] = (_Float16)v0.y;
    hv[2] = (_Float16)v0.z; hv[3] = (_Float16)v0.w;
    hv[4] = (_Float16)v1.x; hv[5] = (_Float16)v1.y;
    hv[6] = (_Float16)v1.z; hv[7] = (_Float16)v1.w;
    *(half8*)(xT + (((size_t)s * B_SZ + b) * I_SZ + i)) = hv;
}

// Wenc[r][0:256]=eWih[r], [256:768]=eWhh[r]  (fp16)
__global__ void k_wenc(const float* __restrict__ eWih, const float* __restrict__ eWhh,
                       _Float16* __restrict__ Wenc) {
    int idx = blockIdx.x * blockDim.x + threadIdx.x;
    int r = idx / 768, col = idx % 768;
    float v = (col < 256) ? eWih[(size_t)r * 256 + col] : eWhh[(size_t)r * 512 + col - 256];
    Wenc[idx] = (_Float16)v;
}

// Wd[r,k] = dWhh[r,k] + sum_o dWih[r,o] * fcW[o,k]
__global__ __launch_bounds__(256) void k_wd(
    const float* __restrict__ dWhh, const float* __restrict__ dWih,
    const float* __restrict__ fcW, _Float16* __restrict__ Wd)
{
    __shared__ float sA[8][256];
    const int tid = threadIdx.x;
    const int r0 = blockIdx.x * 8;
    {
        int linear = tid * 8;
        int row = linear >> 8, col = linear & 255;
        const float4* p = (const float4*)(dWih + (size_t)(r0 + row) * 256 + col);
        float4 v0 = p[0], v1 = p[1];
        *(float4*)&sA[row][col]     = v0;
        *(float4*)&sA[row][col + 4] = v1;
    }
    __syncthreads();
    float acc[8][2] = {};
    const int k = tid;
    for (int i = 0; i < 256; ++i) {
        float w0 = fcW[(size_t)i * 512 + k];
        float w1 = fcW[(size_t)i * 512 + k + 256];
        #pragma unroll
        for (int rr = 0; rr < 8; ++rr) {
            float a = sA[rr][i];
            acc[rr][0] += a * w0;
            acc[rr][1] += a * w1;
        }
    }
    #pragma unroll
    for (int rr = 0; rr < 8; ++rr) {
        size_t base = (size_t)(r0 + rr) * 512;
        Wd[base + k]       = (_Float16)(dWhh[base + k]       + acc[rr][0]);
        Wd[base + k + 256] = (_Float16)(dWhh[base + k + 256] + acc[rr][1]);
    }
}

// bd[r] = db[r] + sum_o dWih[r,o] * fcb[o]
__global__ __launch_bounds__(256) void k_bd(
    const float* __restrict__ dWih, const float* __restrict__ fcb,
    const float* __restrict__ db, float* __restrict__ bd)
{
    __shared__ float sf[256];
    const int tid = threadIdx.x;
    sf[tid] = fcb[tid];
    __syncthreads();
    int r = blockIdx.x * 256 + tid;
    float acc = db[r];
    const float* row = dWih + (size_t)r * 256;
    for (int o = 0; o < 256; o += 4) {
        float4 v = *(const float4*)(row + o);
        acc += v.x * sf[o] + v.y * sf[o + 1] + v.z * sf[o + 2] + v.w * sf[o + 3];
    }
    bd[r] = acc;
}

// ---------------- persistent whole-recurrence kernel ----------------
// 512 blocks x 256 thr, exactly 2 blocks/CU. The recurrence decomposes by
// batch tile: h[m0:m0+128] is produced AND consumed by exactly the 16 blocks
// sharing mb. So: per-mb 16-block barriers (relaxed spin, one acquire), and
// each XCD hosts 4 complete mb-groups so h/x/W exchange stays in its L2.
__global__ __launch_bounds__(256, 2) void k_lstm_all(
    const _Float16* __restrict__ xT,     // [S][B][256] fp16
    const _Float16* __restrict__ Wenc,   // [2048][768]
    const _Float16* __restrict__ dWhh_h, // [2048][512]
    const _Float16* __restrict__ Wd,     // [2048][512]
    const float* __restrict__ eb, const float* __restrict__ db,
    const float* __restrict__ bd,
    _Float16* __restrict__ h0buf, _Float16* __restrict__ h1buf,
    _Float16* __restrict__ hseq,         // [T+1][B][512]
    unsigned* __restrict__ bar)          // 32 counters, padded 16 uints apart
{
    __shared__ _Float16 lds[2][2][128 * 64];   // 64 KB

    const int tid = threadIdx.x;
    // placement: xcd = blockIdx.x % 8 (dispatch round-robin heuristic);
    // each XCD gets 4 complete mb-groups x 16 jb blocks.
    const int xcd = blockIdx.x & 7, slot = blockIdx.x >> 3;
    const int mb = xcd * 4 + (slot >> 4);
    const int jb = slot & 15;
    const int m0 = mb * 128, j0 = jb * 32;
    unsigned* grp = bar + mb * 16;

    const int wv = tid >> 6, lane = tid & 63, lrow = lane & 15, lk8 = (lane >> 4) * 8;
    const int wm = wv >> 1, wn = wv & 1;

    // staging geometry
    const int colb  = (lane & 7) * 16;
    const int scolh = (colb ^ (((lane >> 3) & 7) << 4)) >> 1;
    int rowq[4], growq[4];
    #pragma unroll
    for (int q = 0; q < 4; ++q) {
        int r = q * 32 + wv * 8 + (lane >> 3);
        rowq[q] = r;
        growq[q] = ((r >> 4) & 3) * H_SZ + j0 + (r >> 6) * 16 + (r & 15);
    }

    // preload the three bias variants for this thread's 4 gate-cols
    float ebj[4], dbj[4], bdj[4];
    #pragma unroll
    for (int nf = 0; nf < 4; ++nf) {
        int col = nf * H_SZ + j0 + wn * 16 + lrow;
        ebj[nf] = eb[col]; dbj[nf] = db[col]; bdj[nf] = bd[col];
    }

    float creg[4][4];   // persistent cell state: [mf][r]
    const int j = j0 + wn * 16 + lrow;

    for (int step = 0; step < NSTEP; ++step) {
        // ---- per-step routing (wave-uniform) ----
        const _Float16* xsrc; const _Float16* hin; const _Float16* W;
        _Float16* hout; int wstride, nx, niter;
        if (step < S_SZ) {
            xsrc = xT + (size_t)step * B_SZ * I_SZ;
            W = Wenc; wstride = 768; nx = 4;
            niter = (step == 0) ? 4 : 12;
            hin  = (step == 0) ? nullptr : ((step & 1) ? h0buf : h1buf);
            hout = (step == S_SZ - 1) ? hseq : ((step & 1) ? h1buf : h0buf);
        } else {
            int t = step - S_SZ;
            xsrc = nullptr; nx = 0; niter = 8; wstride = 512;
            W = (t == 0) ? dWhh_h : Wd;
            hin  = hseq + (size_t)t * BH;
            hout = hseq + (size_t)(t + 1) * BH;
        }

        auto stage = [&](int buf, int it) {
            const int koffW = it * 64;
            const _Float16* Ab; int astr, koffA;
            if (it < nx) { Ab = xsrc; astr = I_SZ; koffA = it * 64; }
            else         { Ab = hin;  astr = H_SZ; koffA = (it - nx) * 64; }
            #pragma unroll
            for (int q = 0; q < 4; ++q) {
                const _Float16* ga = Ab + (size_t)(m0 + rowq[q]) * astr + koffA + scolh;
                GLDS(ga, &lds[buf][0][(q * 256 + wv * 64) * 8]);
            }
            #pragma unroll
            for (int q = 0; q < 4; ++q) {
                const _Float16* gb = W + (size_t)growq[q] * wstride + koffW + scolh;
                GLDS(gb, &lds[buf][1][(q * 256 + wv * 64) * 8]);
            }
        };

        f32x4 acc[4][4];
        #pragma unroll
        for (int mf = 0; mf < 4; ++mf)
            #pragma unroll
            for (int nf = 0; nf < 4; ++nf) {
                f32x4 z = {0.f, 0.f, 0.f, 0.f};
                acc[mf][nf] = z;
            }

        auto compute = [&](int buf) {
            #pragma unroll
            for (int kc = 0; kc < 2; ++kc) {
                const int cb = (kc * 32 + lk8) * 2;
                const int sc = (cb ^ ((lrow & 7) << 4)) >> 1;
                half8 a[4], b[4];
                #pragma unroll
                for (int mf = 0; mf < 4; ++mf)
                    a[mf] = *(const half8*)&lds[buf][0][(wm * 64 + mf * 16 + lrow) * 64 + sc];
                #pragma unroll
                for (int nf = 0; nf < 4; ++nf)
                    b[nf] = *(const half8*)&lds[buf][1][(wn * 64 + nf * 16 + lrow) * 64 + sc];
                #pragma unroll
                for (int mf = 0; mf < 4; ++mf)
                    #pragma unroll
                    for (int nf = 0; nf < 4; ++nf)
                        acc[mf][nf] = __builtin_amdgcn_mfma_f32_16x16x32_f16(a[mf], b[nf], acc[mf][nf], 0, 0, 0);
            }
        };

        stage(0, 0);
        __syncthreads();
        int buf = 0;
        for (int it = 0; it < niter; ++it) {
            if (it + 1 < niter) stage(buf ^ 1, it + 1);
            compute(buf);
            __syncthreads();
            buf ^= 1;
        }

        // ---- epilogue ----
        float bj[4];
        #pragma unroll
        for (int nf = 0; nf < 4; ++nf)
            bj[nf] = (step < S_SZ) ? ebj[nf] : ((step == S_SZ) ? dbj[nf] : bdj[nf]);

        #pragma unroll
        for (int mf = 0; mf < 4; ++mf)
            #pragma unroll
            for (int r = 0; r < 4; ++r) {
                int m = m0 + wm * 64 + mf * 16 + (lane >> 4) * 4 + r;
                float gi = acc[mf][0][r] + bj[0];
                float gf = acc[mf][1][r] + bj[1];
                float gg = acc[mf][2][r] + bj[2];
                float go = acc[mf][3][r] + bj[3];
                float cold = (step == 0) ? 0.0f : creg[mf][r];
                float cn = sigm(gf) * cold + sigm(gi) * tanh_fast(gg);
                creg[mf][r] = cn;
                hout[(size_t)m * H_SZ + j] = (_Float16)(sigm(go) * tanh_fast(cn));
            }

        // ---- per-mb group barrier (16 blocks; relaxed spin, acquire once) ----
        if (step != NSTEP - 1) {
            __syncthreads();
            if (tid == 0) {
                __threadfence();
                __hip_atomic_fetch_add(grp, 1u, __ATOMIC_RELEASE, __HIP_MEMORY_SCOPE_AGENT);
                unsigned target = (unsigned)(step + 1) * 16u;
                while (__hip_atomic_load(grp, __ATOMIC_RELAXED, __HIP_MEMORY_SCOPE_AGENT) < target)
                    __builtin_amdgcn_s_sleep(1);
                __threadfence();
            }
            __syncthreads();
        }
    }
}

// ---------------- batched final FC over all decoder h's ----------------
__global__ __launch_bounds__(256) void k_fc(
    const _Float16* __restrict__ hseq1,  // [T][B][512]
    const _Float16* __restrict__ W,      // fcW fp16 [256][512]
    const float* __restrict__ bias,      // [256]
    float* __restrict__ out)
{
    __shared__ _Float16 Asm[128][PAD];
    __shared__ _Float16 Bsm[128][PAD];

    const int tid = threadIdx.x;
    const int m0 = blockIdx.x * 128;
    const int t  = blockIdx.y;
    const int n0 = blockIdx.z * 128;
    const int wv = tid >> 6, lane = tid & 63, lrow = lane & 15, lk = (lane >> 4) * 8;
    const int wm = wv >> 1, wn = wv & 1;

    f32x4 acc[4][4] = {};

    const int srow = tid >> 3, skc = (tid & 7) * 8;
    const _Float16* A = hseq1 + (size_t)t * BH;

    for (int k0 = 0; k0 < H_SZ; k0 += 64) {
        __syncthreads();
        #pragma unroll
        for (int q = 0; q < 4; ++q) {
            int r = srow + q * 32;
            *(half8*)&Asm[r][skc] = *(const half8*)(A + (size_t)(m0 + r) * H_SZ + k0 + skc);
        }
        #pragma unroll
        for (int q = 0; q < 4; ++q) {
            int rr = srow + q * 32;
            *(half8*)&Bsm[rr][skc] = *(const half8*)(W + (size_t)(n0 + rr) * H_SZ + k0 + skc);
        }
        __syncthreads();
        #pragma unroll
        for (int kc = 0; kc < 64; kc += 32) {
            half8 a[4], b[4];
            #pragma unroll
            for (int mf = 0; mf < 4; ++mf) a[mf] = *(const half8*)&Asm[wm * 64 + mf * 16 + lrow][kc + lk];
            #pragma unroll
            for (int nf = 0; nf < 4; ++nf) b[nf] = *(const half8*)&Bsm[wn * 64 + nf * 16 + lrow][kc + lk];
            #pragma unroll
            for (int mf = 0; mf < 4; ++mf)
                #pragma unroll
                for (int nf = 0; nf < 4; ++nf)
                    acc[mf][nf] = __builtin_amdgcn_mfma_f32_16x16x32_f16(a[mf], b[nf], acc[mf][nf], 0, 0, 0);
        }
    }

    #pragma unroll
    for (int mf = 0; mf < 4; ++mf)
        #pragma unroll
        for (int nf = 0; nf < 4; ++nf) {
            int o = n0 + wn * 64 + nf * 16 + lrow;
            float bv = bias[o];
            #pragma unroll
            for (int r = 0; r < 4; ++r) {
                int m = m0 + wm * 64 + mf * 16 + (lane >> 4) * 4 + r;
                out[(size_t)m * (T_SZ * O_SZ) + (size_t)t * O_SZ + o] = acc[mf][nf][r] + bv;
            }
        }
}

extern "C" void kernel_launch(void* const* d_in, const int* in_sizes, int n_in,
                              void* d_out, int out_size, void* d_ws, size_t ws_size,
                              hipStream_t stream) {
    (void)in_sizes; (void)n_in; (void)out_size; (void)ws_size;

    const float* x    = (const float*)d_in[0];
    const float* eWih = (const float*)d_in[1];
    const float* eWhh = (const float*)d_in[2];
    const float* ebih = (const float*)d_in[3];
    const float* ebhh = (const float*)d_in[4];
    const float* dWih = (const float*)d_in[5];
    const float* dWhh = (const float*)d_in[6];
    const float* dbih = (const float*)d_in[7];
    const float* dbhh = (const float*)d_in[8];
    const float* fcW  = (const float*)d_in[9];
    const float* fcb  = (const float*)d_in[10];
    float* out = (float*)d_out;
    char* ws = (char*)d_ws;

    size_t off = 0;
    auto alloc = [&](size_t bytes) -> void* {
        void* p = ws + off;
        off += (bytes + 255) & ~(size_t)255;
        return p;
    };
    _Float16* xT     = (_Float16*)alloc((size_t)S_SZ * B_SZ * I_SZ * 2);
    _Float16* Wenc   = (_Float16*)alloc((size_t)G4H * (I_SZ + H_SZ) * 2);
    _Float16* dWhh_h = (_Float16*)alloc((size_t)G4H * H_SZ * 2);
    _Float16* Wd     = (_Float16*)alloc((size_t)G4H * H_SZ * 2);
    _Float16* fcW_h  = (_Float16*)alloc((size_t)O_SZ * H_SZ * 2);
    float*    eb     = (float*)alloc(G4H * 4);
    float*    db     = (float*)alloc(G4H * 4);
    float*    bd     = (float*)alloc(G4H * 4);
    _Float16* h0     = (_Float16*)alloc(BH * 2);
    _Float16* h1     = (_Float16*)alloc(BH * 2);
    _Float16* hseq   = (_Float16*)alloc((size_t)(T_SZ + 1) * BH * 2);
    unsigned* bar    = (unsigned*)alloc(32 * 16 * 4);

    const int nWhh = G4H * H_SZ;
    const int nFc  = O_SZ * H_SZ;
    const size_t nX = (size_t)B_SZ * S_SZ * I_SZ;

    k_zeroN<<<2, 256, 0, stream>>>(bar, 32 * 16);
    k_cvt_x<<<(int)(nX / 8 / 256), 256, 0, stream>>>(x, xT);
    k_wenc<<<(G4H * 768) / 256, 256, 0, stream>>>(eWih, eWhh, Wenc);
    k_cvt<<<(nWhh + 255) / 256, 256, 0, stream>>>(dWhh, dWhh_h, nWhh);
    k_cvt<<<(nFc + 255) / 256, 256, 0, stream>>>(fcW, fcW_h, nFc);
    k_bias_combine<<<8, 256, 0, stream>>>(ebih, ebhh, eb, G4H);
    k_bias_combine<<<8, 256, 0, stream>>>(dbih, dbhh, db, G4H);
    k_wd<<<256, 256, 0, stream>>>(dWhh, dWih, fcW, Wd);
    k_bd<<<8, 256, 0, stream>>>(dWih, fcb, db, bd);

    k_lstm_all<<<NB, 256, 0, stream>>>(xT, Wenc, dWhh_h, Wd, eb, db, bd,
                                       h0, h1, hseq, bar);

    k_fc<<<dim3(B_SZ / 128, T_SZ, O_SZ / 128), 256, 0, stream>>>(
        hseq + BH, fcW_h, fcb, out);
}

// Round 6
// 1512.210 us; speedup vs baseline: 3.9220x; 2.4505x over previous
//
#include <hip/hip_runtime.h>

#define I_SZ 256
#define H_SZ 512
#define O_SZ 256
#define B_SZ 4096
#define S_SZ 50
#define T_SZ 20
#define G4H  2048
#define BH   ((size_t)B_SZ * H_SZ)
#define NB   512                 // persistent grid: 2 blocks/CU x 256 CUs
#define NSTEP (S_SZ + T_SZ)

#define PAD 72   // k_fc only

typedef _Float16 half8 __attribute__((ext_vector_type(8)));
typedef float f32x4 __attribute__((ext_vector_type(4)));

__device__ __forceinline__ float sigm(float x) {
    return 1.0f / (1.0f + __expf(-x));
}
__device__ __forceinline__ float tanh_fast(float x) {
    float e = __expf(2.0f * x);
    return 1.0f - 2.0f / (e + 1.0f);
}

// async global->LDS, 16B/lane, linear LDS dest. aux = CPol raw bits:
//   0  -> cached (L1+L2)                    : W, x (read-only, L2-resident)
//   17 -> sc0|sc1 (bypass L1+L2, read LLC)  : h produced by other blocks
#define GLDS(gp, lp, aux) __builtin_amdgcn_global_load_lds(                 \
    (const __attribute__((address_space(1))) void*)(gp),                    \
    (__attribute__((address_space(3))) void*)(lp), 16, 0, (aux))

// ---------------- one-time prep kernels ----------------
__global__ void k_zeroN(unsigned* p, int n) {
    int i = blockIdx.x * blockDim.x + threadIdx.x;
    if (i < n) p[i] = 0u;
}

__global__ void k_cvt(const float* __restrict__ src, _Float16* __restrict__ dst, int n) {
    int i = blockIdx.x * blockDim.x + threadIdx.x;
    if (i < n) dst[i] = (_Float16)src[i];
}

__global__ void k_bias_combine(const float* __restrict__ a, const float* __restrict__ b,
                               float* __restrict__ dst, int n) {
    int i = blockIdx.x * blockDim.x + threadIdx.x;
    if (i < n) dst[i] = a[i] + b[i];
}

// x [B][S][I] fp32 -> xT [S][B][I] fp16
__global__ __launch_bounds__(256) void k_cvt_x(const float* __restrict__ x,
                                               _Float16* __restrict__ xT) {
    size_t idx = ((size_t)blockIdx.x * 256 + threadIdx.x) * 8;
    int i = (int)(idx & 255);
    int s = (int)((idx >> 8) % S_SZ);
    size_t b = idx / (256 * S_SZ);
    float4 v0 = *(const float4*)(x + idx);
    float4 v1 = *(const float4*)(x + idx + 4);
    half8 hv;
    hv[0] = (_Float16)v0.x; hv[1] = (_Float16)v0.y;
    hv[2] = (_Float16)v0.z; hv[3] = (_Float16)v0.w;
    hv[4] = (_Float16)v1.x; hv[5] = (_Float16)v1.y;
    hv[6] = (_Float16)v1.z; hv[7] = (_Float16)v1.w;
    *(half8*)(xT + (((size_t)s * B_SZ + b) * I_SZ + i)) = hv;
}

// Wenc[r][0:256]=eWih[r], [256:768]=eWhh[r]  (fp16)
__global__ void k_wenc(const float* __restrict__ eWih, const float* __restrict__ eWhh,
                       _Float16* __restrict__ Wenc) {
    int idx = blockIdx.x * blockDim.x + threadIdx.x;
    int r = idx / 768, col = idx % 768;
    float v = (col < 256) ? eWih[(size_t)r * 256 + col] : eWhh[(size_t)r * 512 + col - 256];
    Wenc[idx] = (_Float16)v;
}

// Wd[r,k] = dWhh[r,k] + sum_o dWih[r,o] * fcW[o,k]
__global__ __launch_bounds__(256) void k_wd(
    const float* __restrict__ dWhh, const float* __restrict__ dWih,
    const float* __restrict__ fcW, _Float16* __restrict__ Wd)
{
    __shared__ float sA[8][256];
    const int tid = threadIdx.x;
    const int r0 = blockIdx.x * 8;
    {
        int linear = tid * 8;
        int row = linear >> 8, col = linear & 255;
        const float4* p = (const float4*)(dWih + (size_t)(r0 + row) * 256 + col);
        float4 v0 = p[0], v1 = p[1];
        *(float4*)&sA[row][col]     = v0;
        *(float4*)&sA[row][col + 4] = v1;
    }
    __syncthreads();
    float acc[8][2] = {};
    const int k = tid;
    for (int i = 0; i < 256; ++i) {
        float w0 = fcW[(size_t)i * 512 + k];
        float w1 = fcW[(size_t)i * 512 + k + 256];
        #pragma unroll
        for (int rr = 0; rr < 8; ++rr) {
            float a = sA[rr][i];
            acc[rr][0] += a * w0;
            acc[rr][1] += a * w1;
        }
    }
    #pragma unroll
    for (int rr = 0; rr < 8; ++rr) {
        size_t base = (size_t)(r0 + rr) * 512;
        Wd[base + k]       = (_Float16)(dWhh[base + k]       + acc[rr][0]);
        Wd[base + k + 256] = (_Float16)(dWhh[base + k + 256] + acc[rr][1]);
    }
}

// bd[r] = db[r] + sum_o dWih[r,o] * fcb[o]
__global__ __launch_bounds__(256) void k_bd(
    const float* __restrict__ dWih, const float* __restrict__ fcb,
    const float* __restrict__ db, float* __restrict__ bd)
{
    __shared__ float sf[256];
    const int tid = threadIdx.x;
    sf[tid] = fcb[tid];
    __syncthreads();
    int r = blockIdx.x * 256 + tid;
    float acc = db[r];
    const float* row = dWih + (size_t)r * 256;
    for (int o = 0; o < 256; o += 4) {
        float4 v = *(const float4*)(row + o);
        acc += v.x * sf[o] + v.y * sf[o + 1] + v.z * sf[o + 2] + v.w * sf[o + 3];
    }
    bd[r] = acc;
}

// ---------------- persistent whole-recurrence kernel ----------------
// NO acquire/release fences anywhere (they invalidate L2 -> W refetch storm).
// Cross-block h goes through LLC: relaxed agent atomic stores (sc-coherent),
// reads via global_load_lds aux=17 (bypass L1+L2). W/x stay cached in L2 for
// the whole 70-step chain. Barrier = relaxed add + relaxed poll, waited
// mid-loop so encoder x-iterations hide the latency.
__global__ __launch_bounds__(256, 2) void k_lstm_all(
    const _Float16* __restrict__ xT,     // [S][B][256] fp16
    const _Float16* __restrict__ Wenc,   // [2048][768]
    const _Float16* __restrict__ dWhh_h, // [2048][512]
    const _Float16* __restrict__ Wd,     // [2048][512]
    const float* __restrict__ eb, const float* __restrict__ db,
    const float* __restrict__ bd,
    _Float16* __restrict__ h0buf, _Float16* __restrict__ h1buf,
    _Float16* __restrict__ hseq,         // [T+1][B][512]
    unsigned* __restrict__ bar)          // 32 counters, 16 uints apart
{
    __shared__ _Float16 lds[2][2][128 * 64];   // 64 KB

    const int tid = threadIdx.x;
    const int xcd = blockIdx.x & 7, slot = blockIdx.x >> 3;
    const int mb = xcd * 4 + (slot >> 4);
    const int jb = slot & 15;
    const int m0 = mb * 128, j0 = jb * 32;
    unsigned* grp = bar + mb * 16;

    const int wv = tid >> 6, lane = tid & 63, lrow = lane & 15, lk8 = (lane >> 4) * 8;
    const int wm = wv >> 1, wn = wv & 1;

    // staging geometry
    const int colb  = (lane & 7) * 16;
    const int scolh = (colb ^ (((lane >> 3) & 7) << 4)) >> 1;
    int rowq[4], growq[4];
    #pragma unroll
    for (int q = 0; q < 4; ++q) {
        int r = q * 32 + wv * 8 + (lane >> 3);
        rowq[q] = r;
        growq[q] = ((r >> 4) & 3) * H_SZ + j0 + (r >> 6) * 16 + (r & 15);
    }

    float ebj[4], dbj[4], bdj[4];
    #pragma unroll
    for (int nf = 0; nf < 4; ++nf) {
        int col = nf * H_SZ + j0 + wn * 16 + lrow;
        ebj[nf] = eb[col]; dbj[nf] = db[col]; bdj[nf] = bd[col];
    }

    float creg[4][4];   // persistent cell state [mf][r]

    for (int step = 0; step < NSTEP; ++step) {
        // ---- per-step routing (block-uniform) ----
        const _Float16* xsrc; const _Float16* hin; const _Float16* W;
        _Float16* hout; int wstride, nx, niter;
        if (step < S_SZ) {
            xsrc = xT + (size_t)step * B_SZ * I_SZ;
            W = Wenc; wstride = 768; nx = 4;
            niter = (step == 0) ? 4 : 12;
            hin  = (step == 0) ? nullptr : ((step & 1) ? h0buf : h1buf);
            hout = (step == S_SZ - 1) ? hseq : ((step & 1) ? h1buf : h0buf);
        } else {
            int t = step - S_SZ;
            xsrc = nullptr; nx = 0; niter = 8; wstride = 512;
            W = (t == 0) ? dWhh_h : Wd;
            hin  = hseq + (size_t)t * BH;
            hout = hseq + (size_t)(t + 1) * BH;
        }

        auto wait_group = [&]() {
            if (tid == 0) {
                unsigned target = (unsigned)step * 16u;
                while (__hip_atomic_load(grp, __ATOMIC_RELAXED, __HIP_MEMORY_SCOPE_AGENT) < target)
                    __builtin_amdgcn_s_sleep(1);
            }
            __syncthreads();
        };

        auto stage = [&](int buf, int it) {
            const int koffW = it * 64;
            #pragma unroll
            for (int q = 0; q < 4; ++q) {
                const _Float16* gb = W + (size_t)growq[q] * wstride + koffW + scolh;
                GLDS(gb, &lds[buf][1][(q * 256 + wv * 64) * 8], 0);
            }
            if (it < nx) {
                #pragma unroll
                for (int q = 0; q < 4; ++q) {
                    const _Float16* ga = xsrc + (size_t)(m0 + rowq[q]) * I_SZ + it * 64 + scolh;
                    GLDS(ga, &lds[buf][0][(q * 256 + wv * 64) * 8], 0);
                }
            } else {
                #pragma unroll
                for (int q = 0; q < 4; ++q) {
                    const _Float16* ga = hin + (size_t)(m0 + rowq[q]) * H_SZ + (it - nx) * 64 + scolh;
                    GLDS(ga, &lds[buf][0][(q * 256 + wv * 64) * 8], 17);  // sc0|sc1
                }
            }
        };

        f32x4 acc[4][4];
        #pragma unroll
        for (int mf = 0; mf < 4; ++mf)
            #pragma unroll
            for (int nf = 0; nf < 4; ++nf) {
                f32x4 z = {0.f, 0.f, 0.f, 0.f};
                acc[mf][nf] = z;
            }

        auto compute = [&](int buf) {
            #pragma unroll
            for (int kc = 0; kc < 2; ++kc) {
                const int cb = (kc * 32 + lk8) * 2;
                const int sc = (cb ^ ((lrow & 7) << 4)) >> 1;
                half8 a[4], b[4];
                #pragma unroll
                for (int mf = 0; mf < 4; ++mf)
                    a[mf] = *(const half8*)&lds[buf][0][(wm * 64 + mf * 16 + lrow) * 64 + sc];
                #pragma unroll
                for (int nf = 0; nf < 4; ++nf)
                    b[nf] = *(const half8*)&lds[buf][1][(wn * 64 + nf * 16 + lrow) * 64 + sc];
                #pragma unroll
                for (int mf = 0; mf < 4; ++mf)
                    #pragma unroll
                    for (int nf = 0; nf < 4; ++nf)
                        acc[mf][nf] = __builtin_amdgcn_mfma_f32_16x16x32_f16(a[mf], b[nf], acc[mf][nf], 0, 0, 0);
            }
        };

        // decoder steps depend on h immediately
        if (step > 0 && nx == 0) wait_group();
        stage(0, 0);
        __syncthreads();
        int buf = 0;
        for (int it = 0; it < niter; ++it) {
            if (it + 1 < niter) {
                if (step > 0 && it + 1 == nx) wait_group();  // before first h stage
                stage(buf ^ 1, it + 1);
            }
            compute(buf);
            __syncthreads();
            buf ^= 1;
        }

        // ---- epilogue: activations + cell update; repack h via LDS ----
        float bj[4];
        #pragma unroll
        for (int nf = 0; nf < 4; ++nf)
            bj[nf] = (step < S_SZ) ? ebj[nf] : ((step == S_SZ) ? dbj[nf] : bdj[nf]);

        _Float16* hsm = &lds[0][0][0];   // [128][32] halves (free after loop)
        const int lc = wn * 16 + lrow;
        #pragma unroll
        for (int mf = 0; mf < 4; ++mf)
            #pragma unroll
            for (int r = 0; r < 4; ++r) {
                int lr = wm * 64 + mf * 16 + (lane >> 4) * 4 + r;
                float gi = acc[mf][0][r] + bj[0];
                float gf = acc[mf][1][r] + bj[1];
                float gg = acc[mf][2][r] + bj[2];
                float go = acc[mf][3][r] + bj[3];
                float cold = (step == 0) ? 0.0f : creg[mf][r];
                float cn = sigm(gf) * cold + sigm(gi) * tanh_fast(gg);
                creg[mf][r] = cn;
                hsm[lr * 32 + lc] = (_Float16)(sigm(go) * tanh_fast(cn));
            }
        __syncthreads();
        {
            // 2 threads/row, 4x u64 coalesced device-coherent stores each
            int row = tid >> 1, seg = tid & 1;
            const unsigned long long* src =
                (const unsigned long long*)&hsm[row * 32 + seg * 16];
            unsigned long long v0 = src[0], v1 = src[1], v2 = src[2], v3 = src[3];
            unsigned long long* dst =
                (unsigned long long*)(hout + (size_t)(m0 + row) * H_SZ + j0 + seg * 16);
            __hip_atomic_store(dst + 0, v0, __ATOMIC_RELAXED, __HIP_MEMORY_SCOPE_AGENT);
            __hip_atomic_store(dst + 1, v1, __ATOMIC_RELAXED, __HIP_MEMORY_SCOPE_AGENT);
            __hip_atomic_store(dst + 2, v2, __ATOMIC_RELAXED, __HIP_MEMORY_SCOPE_AGENT);
            __hip_atomic_store(dst + 3, v3, __ATOMIC_RELAXED, __HIP_MEMORY_SCOPE_AGENT);
        }

        // ---- arrival (stores complete at the syncthreads-drained waitcnt) ----
        if (step != NSTEP - 1) {
            __syncthreads();
            if (tid == 0)
                __hip_atomic_fetch_add(grp, 1u, __ATOMIC_RELAXED, __HIP_MEMORY_SCOPE_AGENT);
        }
    }
}

// ---------------- batched final FC over all decoder h's ----------------
__global__ __launch_bounds__(256) void k_fc(
    const _Float16* __restrict__ hseq1,  // [T][B][512]
    const _Float16* __restrict__ W,      // fcW fp16 [256][512]
    const float* __restrict__ bias,      // [256]
    float* __restrict__ out)
{
    __shared__ _Float16 Asm[128][PAD];
    __shared__ _Float16 Bsm[128][PAD];

    const int tid = threadIdx.x;
    const int m0 = blockIdx.x * 128;
    const int t  = blockIdx.y;
    const int n0 = blockIdx.z * 128;
    const int wv = tid >> 6, lane = tid & 63, lrow = lane & 15, lk = (lane >> 4) * 8;
    const int wm = wv >> 1, wn = wv & 1;

    f32x4 acc[4][4] = {};

    const int srow = tid >> 3, skc = (tid & 7) * 8;
    const _Float16* A = hseq1 + (size_t)t * BH;

    for (int k0 = 0; k0 < H_SZ; k0 += 64) {
        __syncthreads();
        #pragma unroll
        for (int q = 0; q < 4; ++q) {
            int r = srow + q * 32;
            *(half8*)&Asm[r][skc] = *(const half8*)(A + (size_t)(m0 + r) * H_SZ + k0 + skc);
        }
        #pragma unroll
        for (int q = 0; q < 4; ++q) {
            int rr = srow + q * 32;
            *(half8*)&Bsm[rr][skc] = *(const half8*)(W + (size_t)(n0 + rr) * H_SZ + k0 + skc);
        }
        __syncthreads();
        #pragma unroll
        for (int kc = 0; kc < 64; kc += 32) {
            half8 a[4], b[4];
            #pragma unroll
            for (int mf = 0; mf < 4; ++mf) a[mf] = *(const half8*)&Asm[wm * 64 + mf * 16 + lrow][kc + lk];
            #pragma unroll
            for (int nf = 0; nf < 4; ++nf) b[nf] = *(const half8*)&Bsm[wn * 64 + nf * 16 + lrow][kc + lk];
            #pragma unroll
            for (int mf = 0; mf < 4; ++mf)
                #pragma unroll
                for (int nf = 0; nf < 4; ++nf)
                    acc[mf][nf] = __builtin_amdgcn_mfma_f32_16x16x32_f16(a[mf], b[nf], acc[mf][nf], 0, 0, 0);
        }
    }

    #pragma unroll
    for (int mf = 0; mf < 4; ++mf)
        #pragma unroll
        for (int nf = 0; nf < 4; ++nf) {
            int o = n0 + wn * 64 + nf * 16 + lrow;
            float bv = bias[o];
            #pragma unroll
            for (int r = 0; r < 4; ++r) {
                int m = m0 + wm * 64 + mf * 16 + (lane >> 4) * 4 + r;
                out[(size_t)m * (T_SZ * O_SZ) + (size_t)t * O_SZ + o] = acc[mf][nf][r] + bv;
            }
        }
}

extern "C" void kernel_launch(void* const* d_in, const int* in_sizes, int n_in,
                              void* d_out, int out_size, void* d_ws, size_t ws_size,
                              hipStream_t stream) {
    (void)in_sizes; (void)n_in; (void)out_size; (void)ws_size;

    const float* x    = (const float*)d_in[0];
    const float* eWih = (const float*)d_in[1];
    const float* eWhh = (const float*)d_in[2];
    const float* ebih = (const float*)d_in[3];
    const float* ebhh = (const float*)d_in[4];
    const float* dWih = (const float*)d_in[5];
    const float* dWhh = (const float*)d_in[6];
    const float* dbih = (const float*)d_in[7];
    const float* dbhh = (const float*)d_in[8];
    const float* fcW  = (const float*)d_in[9];
    const float* fcb  = (const float*)d_in[10];
    float* out = (float*)d_out;
    char* ws = (char*)d_ws;

    size_t off = 0;
    auto alloc = [&](size_t bytes) -> void* {
        void* p = ws + off;
        off += (bytes + 255) & ~(size_t)255;
        return p;
    };
    _Float16* xT     = (_Float16*)alloc((size_t)S_SZ * B_SZ * I_SZ * 2);
    _Float16* Wenc   = (_Float16*)alloc((size_t)G4H * (I_SZ + H_SZ) * 2);
    _Float16* dWhh_h = (_Float16*)alloc((size_t)G4H * H_SZ * 2);
    _Float16* Wd     = (_Float16*)alloc((size_t)G4H * H_SZ * 2);
    _Float16* fcW_h  = (_Float16*)alloc((size_t)O_SZ * H_SZ * 2);
    float*    eb     = (float*)alloc(G4H * 4);
    float*    db     = (float*)alloc(G4H * 4);
    float*    bd     = (float*)alloc(G4H * 4);
    _Float16* h0     = (_Float16*)alloc(BH * 2);
    _Float16* h1     = (_Float16*)alloc(BH * 2);
    _Float16* hseq   = (_Float16*)alloc((size_t)(T_SZ + 1) * BH * 2);
    unsigned* bar    = (unsigned*)alloc(32 * 16 * 4);

    const int nWhh = G4H * H_SZ;
    const int nFc  = O_SZ * H_SZ;
    const size_t nX = (size_t)B_SZ * S_SZ * I_SZ;

    k_zeroN<<<2, 256, 0, stream>>>(bar, 32 * 16);
    k_cvt_x<<<(int)(nX / 8 / 256), 256, 0, stream>>>(x, xT);
    k_wenc<<<(G4H * 768) / 256, 256, 0, stream>>>(eWih, eWhh, Wenc);
    k_cvt<<<(nWhh + 255) / 256, 256, 0, stream>>>(dWhh, dWhh_h, nWhh);
    k_cvt<<<(nFc + 255) / 256, 256, 0, stream>>>(fcW, fcW_h, nFc);
    k_bias_combine<<<8, 256, 0, stream>>>(ebih, ebhh, eb, G4H);
    k_bias_combine<<<8, 256, 0, stream>>>(dbih, dbhh, db, G4H);
    k_wd<<<256, 256, 0, stream>>>(dWhh, dWih, fcW, Wd);
    k_bd<<<8, 256, 0, stream>>>(dWih, fcb, db, bd);

    k_lstm_all<<<NB, 256, 0, stream>>>(xT, Wenc, dWhh_h, Wd, eb, db, bd,
                                       h0, h1, hseq, bar);

    k_fc<<<dim3(B_SZ / 128, T_SZ, O_SZ / 128), 256, 0, stream>>>(
        hseq + BH, fcW_h, fcb, out);
}

// Round 7
// 1331.128 us; speedup vs baseline: 4.4555x; 1.1360x over previous
//
#include <hip/hip_runtime.h>

#define I_SZ 256
#define H_SZ 512
#define O_SZ 256
#define B_SZ 4096
#define S_SZ 50
#define T_SZ 20
#define G4H  2048
#define BH   ((size_t)B_SZ * H_SZ)
#define NB   512                 // persistent grid: 2 blocks/CU x 256 CUs
#define NSTEP (S_SZ + T_SZ)

#define PAD 72    // k_fc only
#define PAD_H 36  // epilogue h repack stride (halves): 72B rows, 8B-aligned, conflict-free writes

typedef _Float16 half8 __attribute__((ext_vector_type(8)));
typedef float f32x4 __attribute__((ext_vector_type(4)));

__device__ __forceinline__ float sigm(float x) {
    return 1.0f / (1.0f + __expf(-x));
}
__device__ __forceinline__ float tanh_fast(float x) {
    float e = __expf(2.0f * x);
    return 1.0f - 2.0f / (e + 1.0f);
}

// async global->LDS, 16B/lane, linear LDS dest. aux = CPol raw bits:
//   0  -> cached (L1+L2)                    : W, x (read-only, L2-resident)
//   17 -> sc0|sc1 (bypass L1+L2, read LLC)  : h produced by other blocks
#define GLDS(gp, lp, aux) __builtin_amdgcn_global_load_lds(                 \
    (const __attribute__((address_space(1))) void*)(gp),                    \
    (__attribute__((address_space(3))) void*)(lp), 16, 0, (aux))

#define MEMFENCE asm volatile("" ::: "memory")

// ---------------- one-time prep kernels ----------------
__global__ void k_zeroN(unsigned* p, int n) {
    int i = blockIdx.x * blockDim.x + threadIdx.x;
    if (i < n) p[i] = 0u;
}

__global__ void k_cvt(const float* __restrict__ src, _Float16* __restrict__ dst, int n) {
    int i = blockIdx.x * blockDim.x + threadIdx.x;
    if (i < n) dst[i] = (_Float16)src[i];
}

__global__ void k_bias_combine(const float* __restrict__ a, const float* __restrict__ b,
                               float* __restrict__ dst, int n) {
    int i = blockIdx.x * blockDim.x + threadIdx.x;
    if (i < n) dst[i] = a[i] + b[i];
}

// x [B][S][I] fp32 -> xT [S][B][I] fp16
__global__ __launch_bounds__(256) void k_cvt_x(const float* __restrict__ x,
                                               _Float16* __restrict__ xT) {
    size_t idx = ((size_t)blockIdx.x * 256 + threadIdx.x) * 8;
    int i = (int)(idx & 255);
    int s = (int)((idx >> 8) % S_SZ);
    size_t b = idx / (256 * S_SZ);
    float4 v0 = *(const float4*)(x + idx);
    float4 v1 = *(const float4*)(x + idx + 4);
    half8 hv;
    hv[0] = (_Float16)v0.x; hv[1] = (_Float16)v0.y;
    hv[2] = (_Float16)v0.z; hv[3] = (_Float16)v0.w;
    hv[4] = (_Float16)v1.x; hv[5] = (_Float16)v1.y;
    hv[6] = (_Float16)v1.z; hv[7] = (_Float16)v1.w;
    *(half8*)(xT + (((size_t)s * B_SZ + b) * I_SZ + i)) = hv;
}

// Wenc[r][0:256]=eWih[r], [256:768]=eWhh[r]  (fp16)
__global__ void k_wenc(const float* __restrict__ eWih, const float* __restrict__ eWhh,
                       _Float16* __restrict__ Wenc) {
    int idx = blockIdx.x * blockDim.x + threadIdx.x;
    int r = idx / 768, col = idx % 768;
    float v = (col < 256) ? eWih[(size_t)r * 256 + col] : eWhh[(size_t)r * 512 + col - 256];
    Wenc[idx] = (_Float16)v;
}

// Wd[r,k] = dWhh[r,k] + sum_o dWih[r,o] * fcW[o,k]
__global__ __launch_bounds__(256) void k_wd(
    const float* __restrict__ dWhh, const float* __restrict__ dWih,
    const float* __restrict__ fcW, _Float16* __restrict__ Wd)
{
    __shared__ float sA[8][256];
    const int tid = threadIdx.x;
    const int r0 = blockIdx.x * 8;
    {
        int linear = tid * 8;
        int row = linear >> 8, col = linear & 255;
        const float4* p = (const float4*)(dWih + (size_t)(r0 + row) * 256 + col);
        float4 v0 = p[0], v1 = p[1];
        *(float4*)&sA[row][col]     = v0;
        *(float4*)&sA[row][col + 4] = v1;
    }
    __syncthreads();
    float acc[8][2] = {};
    const int k = tid;
    for (int i = 0; i < 256; ++i) {
        float w0 = fcW[(size_t)i * 512 + k];
        float w1 = fcW[(size_t)i * 512 + k + 256];
        #pragma unroll
        for (int rr = 0; rr < 8; ++rr) {
            float a = sA[rr][i];
            acc[rr][0] += a * w0;
            acc[rr][1] += a * w1;
        }
    }
    #pragma unroll
    for (int rr = 0; rr < 8; ++rr) {
        size_t base = (size_t)(r0 + rr) * 512;
        Wd[base + k]       = (_Float16)(dWhh[base + k]       + acc[rr][0]);
        Wd[base + k + 256] = (_Float16)(dWhh[base + k + 256] + acc[rr][1]);
    }
}

// bd[r] = db[r] + sum_o dWih[r,o] * fcb[o]
__global__ __launch_bounds__(256) void k_bd(
    const float* __restrict__ dWih, const float* __restrict__ fcb,
    const float* __restrict__ db, float* __restrict__ bd)
{
    __shared__ float sf[256];
    const int tid = threadIdx.x;
    sf[tid] = fcb[tid];
    __syncthreads();
    int r = blockIdx.x * 256 + tid;
    float acc = db[r];
    const float* row = dWih + (size_t)r * 256;
    for (int o = 0; o < 256; o += 4) {
        float4 v = *(const float4*)(row + o);
        acc += v.x * sf[o] + v.y * sf[o + 1] + v.z * sf[o + 2] + v.w * sf[o + 3];
    }
    bd[r] = acc;
}

// ---------------- persistent whole-recurrence kernel ----------------
// No acquire/release fences (L2 stays warm). Cross-block h via LLC: sc-stores
// (full 64B lines per instruction), reads via global_load_lds aux=17.
// K-loop: counted vmcnt + raw s_barrier -> next-iter loads stay in flight
// across the barrier (T4). Group barrier = relaxed add + relaxed poll.
__global__ __launch_bounds__(256, 2) void k_lstm_all(
    const _Float16* __restrict__ xT,     // [S][B][256] fp16
    const _Float16* __restrict__ Wenc,   // [2048][768]
    const _Float16* __restrict__ dWhh_h, // [2048][512]
    const _Float16* __restrict__ Wd,     // [2048][512]
    const float* __restrict__ eb, const float* __restrict__ db,
    const float* __restrict__ bd,
    _Float16* __restrict__ h0buf, _Float16* __restrict__ h1buf,
    _Float16* __restrict__ hseq,         // [T+1][B][512]
    unsigned* __restrict__ bar)          // 32 counters, 16 uints apart
{
    __shared__ _Float16 lds[2][2][128 * 64];   // 64 KB

    const int tid = threadIdx.x;
    const int xcd = blockIdx.x & 7, slot = blockIdx.x >> 3;
    const int mb = xcd * 4 + (slot >> 4);
    const int jb = slot & 15;
    const int m0 = mb * 128, j0 = jb * 32;
    unsigned* grp = bar + mb * 16;

    const int wv = tid >> 6, lane = tid & 63, lrow = lane & 15, lk8 = (lane >> 4) * 8;
    const int wm = wv >> 1, wn = wv & 1;

    // staging geometry
    const int colb  = (lane & 7) * 16;
    const int scolh = (colb ^ (((lane >> 3) & 7) << 4)) >> 1;
    int rowq[4], growq[4];
    #pragma unroll
    for (int q = 0; q < 4; ++q) {
        int r = q * 32 + wv * 8 + (lane >> 3);
        rowq[q] = r;
        growq[q] = ((r >> 4) & 3) * H_SZ + j0 + (r >> 6) * 16 + (r & 15);
    }

    float ebj[4], dbj[4], bdj[4];
    #pragma unroll
    for (int nf = 0; nf < 4; ++nf) {
        int col = nf * H_SZ + j0 + wn * 16 + lrow;
        ebj[nf] = eb[col]; dbj[nf] = db[col]; bdj[nf] = bd[col];
    }

    float creg[4][4];   // persistent cell state [mf][r]

    for (int step = 0; step < NSTEP; ++step) {
        // ---- per-step routing (block-uniform) ----
        const _Float16* xsrc; const _Float16* hin; const _Float16* W;
        _Float16* hout; int wstride, nx, niter;
        if (step < S_SZ) {
            xsrc = xT + (size_t)step * B_SZ * I_SZ;
            W = Wenc; wstride = 768; nx = 4;
            niter = (step == 0) ? 4 : 12;
            hin  = (step == 0) ? nullptr : ((step & 1) ? h0buf : h1buf);
            hout = (step == S_SZ - 1) ? hseq : ((step & 1) ? h1buf : h0buf);
        } else {
            int t = step - S_SZ;
            xsrc = nullptr; nx = 0; niter = 8; wstride = 512;
            W = (t == 0) ? dWhh_h : Wd;
            hin  = hseq + (size_t)t * BH;
            hout = hseq + (size_t)(t + 1) * BH;
        }

        // raw-barrier group wait: tid0 spins (relaxed), s_barrier holds the rest
        auto wait_group = [&]() {
            MEMFENCE;
            if (tid == 0) {
                unsigned target = (unsigned)step * 16u;
                while (__hip_atomic_load(grp, __ATOMIC_RELAXED, __HIP_MEMORY_SCOPE_AGENT) < target)
                    __builtin_amdgcn_s_sleep(1);
            }
            __builtin_amdgcn_s_barrier();
            MEMFENCE;
        };

        auto stage = [&](int buf, int it) {
            const int koffW = it * 64;
            #pragma unroll
            for (int q = 0; q < 4; ++q) {
                const _Float16* gb = W + (size_t)growq[q] * wstride + koffW + scolh;
                GLDS(gb, &lds[buf][1][(q * 256 + wv * 64) * 8], 0);
            }
            if (it < nx) {
                #pragma unroll
                for (int q = 0; q < 4; ++q) {
                    const _Float16* ga = xsrc + (size_t)(m0 + rowq[q]) * I_SZ + it * 64 + scolh;
                    GLDS(ga, &lds[buf][0][(q * 256 + wv * 64) * 8], 0);
                }
            } else {
                #pragma unroll
                for (int q = 0; q < 4; ++q) {
                    const _Float16* ga = hin + (size_t)(m0 + rowq[q]) * H_SZ + (it - nx) * 64 + scolh;
                    GLDS(ga, &lds[buf][0][(q * 256 + wv * 64) * 8], 17);  // sc0|sc1
                }
            }
        };

        f32x4 acc[4][4];
        #pragma unroll
        for (int mf = 0; mf < 4; ++mf)
            #pragma unroll
            for (int nf = 0; nf < 4; ++nf) {
                f32x4 z = {0.f, 0.f, 0.f, 0.f};
                acc[mf][nf] = z;
            }

        auto compute = [&](int buf) {
            #pragma unroll
            for (int kc = 0; kc < 2; ++kc) {
                const int cb = (kc * 32 + lk8) * 2;
                const int sc = (cb ^ ((lrow & 7) << 4)) >> 1;
                half8 a[4], b[4];
                #pragma unroll
                for (int mf = 0; mf < 4; ++mf)
                    a[mf] = *(const half8*)&lds[buf][0][(wm * 64 + mf * 16 + lrow) * 64 + sc];
                #pragma unroll
                for (int nf = 0; nf < 4; ++nf)
                    b[nf] = *(const half8*)&lds[buf][1][(wn * 64 + nf * 16 + lrow) * 64 + sc];
                #pragma unroll
                for (int mf = 0; mf < 4; ++mf)
                    #pragma unroll
                    for (int nf = 0; nf < 4; ++nf)
                        acc[mf][nf] = __builtin_amdgcn_mfma_f32_16x16x32_f16(a[mf], b[nf], acc[mf][nf], 0, 0, 0);
            }
        };

        // ---- pipelined K-loop: counted vmcnt, raw barriers ----
        if (step > 0 && nx == 0) wait_group();   // decoder: h needed immediately
        stage(0, 0);
        int buf = 0;
        for (int it = 0; it < niter; ++it) {
            if (it + 1 < niter) {
                if (step > 0 && nx > 0 && it + 1 == nx) wait_group();  // before first h stage
                stage(buf ^ 1, it + 1);
                asm volatile("s_waitcnt vmcnt(8)" ::: "memory");   // this iter's 8 done
            } else {
                asm volatile("s_waitcnt vmcnt(0)" ::: "memory");
            }
            __builtin_amdgcn_s_barrier();      // all waves' tile ready
            MEMFENCE;
            compute(buf);
            MEMFENCE;
            __builtin_amdgcn_s_barrier();      // all waves done reading buf
            MEMFENCE;
            buf ^= 1;
        }

        // ---- epilogue: activations + cell update; repack h via LDS ----
        float bj[4];
        #pragma unroll
        for (int nf = 0; nf < 4; ++nf)
            bj[nf] = (step < S_SZ) ? ebj[nf] : ((step == S_SZ) ? dbj[nf] : bdj[nf]);

        _Float16* hsm = &lds[0][0][0];   // [128][PAD_H] halves (free after loop)
        const int lc = wn * 16 + lrow;
        #pragma unroll
        for (int mf = 0; mf < 4; ++mf)
            #pragma unroll
            for (int r = 0; r < 4; ++r) {
                int lr = wm * 64 + mf * 16 + (lane >> 4) * 4 + r;
                float gi = acc[mf][0][r] + bj[0];
                float gf = acc[mf][1][r] + bj[1];
                float gg = acc[mf][2][r] + bj[2];
                float go = acc[mf][3][r] + bj[3];
                float cold = (step == 0) ? 0.0f : creg[mf][r];
                float cn = sigm(gf) * cold + sigm(gi) * tanh_fast(gg);
                creg[mf][r] = cn;
                hsm[lr * PAD_H + lc] = (_Float16)(sigm(go) * tanh_fast(cn));
            }
        __syncthreads();
        {
            // 8 lanes/row x u64: each store instruction writes 8 full 64B lines
            int rr = tid >> 3, k = tid & 7;
            #pragma unroll
            for (int q = 0; q < 4; ++q) {
                int r = rr + q * 32;
                unsigned long long v = *(const unsigned long long*)&hsm[r * PAD_H + k * 4];
                unsigned long long* dst =
                    (unsigned long long*)(hout + (size_t)(m0 + r) * H_SZ + j0) + k;
                __hip_atomic_store(dst, v, __ATOMIC_RELAXED, __HIP_MEMORY_SCOPE_AGENT);
            }
        }

        // ---- arrival (syncthreads drains the h stores before signaling) ----
        if (step != NSTEP - 1) {
            __syncthreads();
            if (tid == 0)
                __hip_atomic_fetch_add(grp, 1u, __ATOMIC_RELAXED, __HIP_MEMORY_SCOPE_AGENT);
        }
    }
}

// ---------------- batched final FC over all decoder h's ----------------
__global__ __launch_bounds__(256) void k_fc(
    const _Float16* __restrict__ hseq1,  // [T][B][512]
    const _Float16* __restrict__ W,      // fcW fp16 [256][512]
    const float* __restrict__ bias,      // [256]
    float* __restrict__ out)
{
    __shared__ _Float16 Asm[128][PAD];
    __shared__ _Float16 Bsm[128][PAD];

    const int tid = threadIdx.x;
    const int m0 = blockIdx.x * 128;
    const int t  = blockIdx.y;
    const int n0 = blockIdx.z * 128;
    const int wv = tid >> 6, lane = tid & 63, lrow = lane & 15, lk = (lane >> 4) * 8;
    const int wm = wv >> 1, wn = wv & 1;

    f32x4 acc[4][4] = {};

    const int srow = tid >> 3, skc = (tid & 7) * 8;
    const _Float16* A = hseq1 + (size_t)t * BH;

    for (int k0 = 0; k0 < H_SZ; k0 += 64) {
        __syncthreads();
        #pragma unroll
        for (int q = 0; q < 4; ++q) {
            int r = srow + q * 32;
            *(half8*)&Asm[r][skc] = *(const half8*)(A + (size_t)(m0 + r) * H_SZ + k0 + skc);
        }
        #pragma unroll
        for (int q = 0; q < 4; ++q) {
            int rr = srow + q * 32;
            *(half8*)&Bsm[rr][skc] = *(const half8*)(W + (size_t)(n0 + rr) * H_SZ + k0 + skc);
        }
        __syncthreads();
        #pragma unroll
        for (int kc = 0; kc < 64; kc += 32) {
            half8 a[4], b[4];
            #pragma unroll
            for (int mf = 0; mf < 4; ++mf) a[mf] = *(const half8*)&Asm[wm * 64 + mf * 16 + lrow][kc + lk];
            #pragma unroll
            for (int nf = 0; nf < 4; ++nf) b[nf] = *(const half8*)&Bsm[wn * 64 + nf * 16 + lrow][kc + lk];
            #pragma unroll
            for (int mf = 0; mf < 4; ++mf)
                #pragma unroll
                for (int nf = 0; nf < 4; ++nf)
                    acc[mf][nf] = __builtin_amdgcn_mfma_f32_16x16x32_f16(a[mf], b[nf], acc[mf][nf], 0, 0, 0);
        }
    }

    #pragma unroll
    for (int mf = 0; mf < 4; ++mf)
        #pragma unroll
        for (int nf = 0; nf < 4; ++nf) {
            int o = n0 + wn * 64 + nf * 16 + lrow;
            float bv = bias[o];
            #pragma unroll
            for (int r = 0; r < 4; ++r) {
                int m = m0 + wm * 64 + mf * 16 + (lane >> 4) * 4 + r;
                out[(size_t)m * (T_SZ * O_SZ) + (size_t)t * O_SZ + o] = acc[mf][nf][r] + bv;
            }
        }
}

extern "C" void kernel_launch(void* const* d_in, const int* in_sizes, int n_in,
                              void* d_out, int out_size, void* d_ws, size_t ws_size,
                              hipStream_t stream) {
    (void)in_sizes; (void)n_in; (void)out_size; (void)ws_size;

    const float* x    = (const float*)d_in[0];
    const float* eWih = (const float*)d_in[1];
    const float* eWhh = (const float*)d_in[2];
    const float* ebih = (const float*)d_in[3];
    const float* ebhh = (const float*)d_in[4];
    const float* dWih = (const float*)d_in[5];
    const float* dWhh = (const float*)d_in[6];
    const float* dbih = (const float*)d_in[7];
    const float* dbhh = (const float*)d_in[8];
    const float* fcW  = (const float*)d_in[9];
    const float* fcb  = (const float*)d_in[10];
    float* out = (float*)d_out;
    char* ws = (char*)d_ws;

    size_t off = 0;
    auto alloc = [&](size_t bytes) -> void* {
        void* p = ws + off;
        off += (bytes + 255) & ~(size_t)255;
        return p;
    };
    _Float16* xT     = (_Float16*)alloc((size_t)S_SZ * B_SZ * I_SZ * 2);
    _Float16* Wenc   = (_Float16*)alloc((size_t)G4H * (I_SZ + H_SZ) * 2);
    _Float16* dWhh_h = (_Float16*)alloc((size_t)G4H * H_SZ * 2);
    _Float16* Wd     = (_Float16*)alloc((size_t)G4H * H_SZ * 2);
    _Float16* fcW_h  = (_Float16*)alloc((size_t)O_SZ * H_SZ * 2);
    float*    eb     = (float*)alloc(G4H * 4);
    float*    db     = (float*)alloc(G4H * 4);
    float*    bd     = (float*)alloc(G4H * 4);
    _Float16* h0     = (_Float16*)alloc(BH * 2);
    _Float16* h1     = (_Float16*)alloc(BH * 2);
    _Float16* hseq   = (_Float16*)alloc((size_t)(T_SZ + 1) * BH * 2);
    unsigned* bar    = (unsigned*)alloc(32 * 16 * 4);

    const int nWhh = G4H * H_SZ;
    const int nFc  = O_SZ * H_SZ;
    const size_t nX = (size_t)B_SZ * S_SZ * I_SZ;

    k_zeroN<<<2, 256, 0, stream>>>(bar, 32 * 16);
    k_cvt_x<<<(int)(nX / 8 / 256), 256, 0, stream>>>(x, xT);
    k_wenc<<<(G4H * 768) / 256, 256, 0, stream>>>(eWih, eWhh, Wenc);
    k_cvt<<<(nWhh + 255) / 256, 256, 0, stream>>>(dWhh, dWhh_h, nWhh);
    k_cvt<<<(nFc + 255) / 256, 256, 0, stream>>>(fcW, fcW_h, nFc);
    k_bias_combine<<<8, 256, 0, stream>>>(ebih, ebhh, eb, G4H);
    k_bias_combine<<<8, 256, 0, stream>>>(dbih, dbhh, db, G4H);
    k_wd<<<256, 256, 0, stream>>>(dWhh, dWih, fcW, Wd);
    k_bd<<<8, 256, 0, stream>>>(dWih, fcb, db, bd);

    k_lstm_all<<<NB, 256, 0, stream>>>(xT, Wenc, dWhh_h, Wd, eb, db, bd,
                                       h0, h1, hseq, bar);

    k_fc<<<dim3(B_SZ / 128, T_SZ, O_SZ / 128), 256, 0, stream>>>(
        hseq + BH, fcW_h, fcb, out);
}

// Round 8
// 1270.682 us; speedup vs baseline: 4.6675x; 1.0476x over previous
//
#include <hip/hip_runtime.h>

#define I_SZ 256
#define H_SZ 512
#define O_SZ 256
#define B_SZ 4096
#define S_SZ 50
#define T_SZ 20
#define G4H  2048
#define BH   ((size_t)B_SZ * H_SZ)
#define NB   512                 // persistent grid: 2 blocks/CU x 256 CUs

#define PAD 72    // k_fc only
#define PAD_H 36  // epilogue h repack stride (halves)

typedef _Float16 half8 __attribute__((ext_vector_type(8)));
typedef float f32x4 __attribute__((ext_vector_type(4)));

__device__ __forceinline__ float sigm(float x) {
    return 1.0f / (1.0f + __expf(-x));
}
__device__ __forceinline__ float tanh_fast(float x) {
    float e = __expf(2.0f * x);
    return 1.0f - 2.0f / (e + 1.0f);
}

// async global->LDS, 16B/lane, linear LDS dest. aux=0 -> cached L1+L2.
#define GLDS(gp, lp) __builtin_amdgcn_global_load_lds(                      \
    (const __attribute__((address_space(1))) void*)(gp),                    \
    (__attribute__((address_space(3))) void*)(lp), 16, 0, 0)

#define MEMFENCE asm volatile("" ::: "memory")

// ---------------- one-time prep kernels ----------------
__global__ void k_zeroN(unsigned* p, int n) {
    int i = blockIdx.x * blockDim.x + threadIdx.x;
    if (i < n) p[i] = 0u;
}

__global__ void k_cvt(const float* __restrict__ src, _Float16* __restrict__ dst, int n) {
    int i = blockIdx.x * blockDim.x + threadIdx.x;
    if (i < n) dst[i] = (_Float16)src[i];
}

__global__ void k_bias_combine(const float* __restrict__ a, const float* __restrict__ b,
                               float* __restrict__ dst, int n) {
    int i = blockIdx.x * blockDim.x + threadIdx.x;
    if (i < n) dst[i] = a[i] + b[i];
}

// x [B][S][I] fp32 -> xT [S][B][I] fp16
__global__ __launch_bounds__(256) void k_cvt_x(const float* __restrict__ x,
                                               _Float16* __restrict__ xT) {
    size_t idx = ((size_t)blockIdx.x * 256 + threadIdx.x) * 8;
    int i = (int)(idx & 255);
    int s = (int)((idx >> 8) % S_SZ);
    size_t b = idx / (256 * S_SZ);
    float4 v0 = *(const float4*)(x + idx);
    float4 v1 = *(const float4*)(x + idx + 4);
    half8 hv;
    hv[0] = (_Float16)v0.x; hv[1] = (_Float16)v0.y;
    hv[2] = (_Float16)v0.z; hv[3] = (_Float16)v0.w;
    hv[4] = (_Float16)v1.x; hv[5] = (_Float16)v1.y;
    hv[6] = (_Float16)v1.z; hv[7] = (_Float16)v1.w;
    *(half8*)(xT + (((size_t)s * B_SZ + b) * I_SZ + i)) = hv;
}

// Wenc[r][0:256]=eWih[r], [256:768]=eWhh[r]  (fp16)
__global__ void k_wenc(const float* __restrict__ eWih, const float* __restrict__ eWhh,
                       _Float16* __restrict__ Wenc) {
    int idx = blockIdx.x * blockDim.x + threadIdx.x;
    int r = idx / 768, col = idx % 768;
    float v = (col < 256) ? eWih[(size_t)r * 256 + col] : eWhh[(size_t)r * 512 + col - 256];
    Wenc[idx] = (_Float16)v;
}

// Wd[r,k] = dWhh[r,k] + sum_o dWih[r,o] * fcW[o,k]
__global__ __launch_bounds__(256) void k_wd(
    const float* __restrict__ dWhh, const float* __restrict__ dWih,
    const float* __restrict__ fcW, _Float16* __restrict__ Wd)
{
    __shared__ float sA[8][256];
    const int tid = threadIdx.x;
    const int r0 = blockIdx.x * 8;
    {
        int linear = tid * 8;
        int row = linear >> 8, col = linear & 255;
        const float4* p = (const float4*)(dWih + (size_t)(r0 + row) * 256 + col);
        float4 v0 = p[0], v1 = p[1];
        *(float4*)&sA[row][col]     = v0;
        *(float4*)&sA[row][col + 4] = v1;
    }
    __syncthreads();
    float acc[8][2] = {};
    const int k = tid;
    for (int i = 0; i < 256; ++i) {
        float w0 = fcW[(size_t)i * 512 + k];
        float w1 = fcW[(size_t)i * 512 + k + 256];
        #pragma unroll
        for (int rr = 0; rr < 8; ++rr) {
            float a = sA[rr][i];
            acc[rr][0] += a * w0;
            acc[rr][1] += a * w1;
        }
    }
    #pragma unroll
    for (int rr = 0; rr < 8; ++rr) {
        size_t base = (size_t)(r0 + rr) * 512;
        Wd[base + k]       = (_Float16)(dWhh[base + k]       + acc[rr][0]);
        Wd[base + k + 256] = (_Float16)(dWhh[base + k + 256] + acc[rr][1]);
    }
}

// bd[r] = db[r] + sum_o dWih[r,o] * fcb[o]
__global__ __launch_bounds__(256) void k_bd(
    const float* __restrict__ dWih, const float* __restrict__ fcb,
    const float* __restrict__ db, float* __restrict__ bd)
{
    __shared__ float sf[256];
    const int tid = threadIdx.x;
    sf[tid] = fcb[tid];
    __syncthreads();
    int r = blockIdx.x * 256 + tid;
    float acc = db[r];
    const float* row = dWih + (size_t)r * 256;
    for (int o = 0; o < 256; o += 4) {
        float4 v = *(const float4*)(row + o);
        acc += v.x * sf[o] + v.y * sf[o + 1] + v.z * sf[o + 2] + v.w * sf[o + 3];
    }
    bd[r] = acc;
}

// ---------------- persistent whole-recurrence kernel ----------------
// Unique h slab per step -> no stale-line hazard -> h reads are plain cached
// (L2-hit for 15/16 same-XCD blocks). Producers: sc0|sc1 write-through stores.
// K-loops fully unrolled (compile-time niter); addresses precomputed, it*64
// folds into the load imm offset. Counted vmcnt + raw barriers (T4).
__global__ __launch_bounds__(256, 2) void k_lstm_all(
    const _Float16* __restrict__ xT,     // [S][B][256] fp16
    const _Float16* __restrict__ Wenc,   // [2048][768]
    const _Float16* __restrict__ dWhh_h, // [2048][512]
    const _Float16* __restrict__ Wd,     // [2048][512]
    const float* __restrict__ eb, const float* __restrict__ db,
    const float* __restrict__ bd,
    _Float16* __restrict__ henc,         // [49][B][512] unique slabs (enc steps 0..48)
    _Float16* __restrict__ hseq,         // [21][B][512] (enc 49 -> [0], dec t -> [t+1])
    unsigned* __restrict__ bar)          // 32 counters, 16 uints apart
{
    __shared__ _Float16 lds[2][2][128 * 64];   // 64 KB

    const int tid = threadIdx.x;
    const int xcd = blockIdx.x & 7, slot = blockIdx.x >> 3;
    const int mb = xcd * 4 + (slot >> 4);
    const int jb = slot & 15;
    const int m0 = mb * 128, j0 = jb * 32;
    unsigned* grp = bar + mb * 16;

    const int wv = tid >> 6, lane = tid & 63, lrow = lane & 15, lk8 = (lane >> 4) * 8;
    const int wm = wv >> 1, wn = wv & 1;

    // ---- staging geometry: precomputed per-q pointers ----
    const int colb  = (lane & 7) * 16;
    const int scolh = (colb ^ (((lane >> 3) & 7) << 4)) >> 1;
    const _Float16* wEncQ[4]; const _Float16* wD0Q[4]; const _Float16* wDQ[4];
    const _Float16* xQ[4];
    unsigned aOffQ[4];
    int ldsQ[4];
    #pragma unroll
    for (int q = 0; q < 4; ++q) {
        int r = q * 32 + wv * 8 + (lane >> 3);
        int grow = ((r >> 4) & 3) * H_SZ + j0 + (r >> 6) * 16 + (r & 15);
        wEncQ[q] = Wenc   + (size_t)grow * 768 + scolh;
        wD0Q[q]  = dWhh_h + (size_t)grow * 512 + scolh;
        wDQ[q]   = Wd     + (size_t)grow * 512 + scolh;
        xQ[q]    = xT + (size_t)(m0 + r) * I_SZ + scolh;
        aOffQ[q] = (unsigned)((m0 + r) * H_SZ) + scolh;
        ldsQ[q]  = (q * 256 + wv * 64) * 8;
    }

    float ebj[4], dbj[4], bdj[4];
    #pragma unroll
    for (int nf = 0; nf < 4; ++nf) {
        int col = nf * H_SZ + j0 + wn * 16 + lrow;
        ebj[nf] = eb[col]; dbj[nf] = db[col]; bdj[nf] = bd[col];
    }

    float creg[4][4];

    auto wait_group = [&](unsigned target) {
        MEMFENCE;
        if (tid == 0) {
            while (__hip_atomic_load(grp, __ATOMIC_RELAXED, __HIP_MEMORY_SCOPE_AGENT) < target)
                __builtin_amdgcn_s_sleep(1);
        }
        __builtin_amdgcn_s_barrier();
        MEMFENCE;
    };
    auto arrive = [&]() {
        __syncthreads();   // drains h sc-stores (vmcnt 0) before signaling
        if (tid == 0)
            __hip_atomic_fetch_add(grp, 1u, __ATOMIC_RELAXED, __HIP_MEMORY_SCOPE_AGENT);
    };

    auto compute = [&](int buf, f32x4 (&acc)[4][4]) {
        #pragma unroll
        for (int kc = 0; kc < 2; ++kc) {
            const int sc = (((kc * 32 + lk8) * 2) ^ ((lrow & 7) << 4)) >> 1;
            half8 a[4], b[4];
            #pragma unroll
            for (int mf = 0; mf < 4; ++mf)
                a[mf] = *(const half8*)&lds[buf][0][(wm * 64 + mf * 16 + lrow) * 64 + sc];
            #pragma unroll
            for (int nf = 0; nf < 4; ++nf)
                b[nf] = *(const half8*)&lds[buf][1][(wn * 64 + nf * 16 + lrow) * 64 + sc];
            #pragma unroll
            for (int mf = 0; mf < 4; ++mf)
                #pragma unroll
                for (int nf = 0; nf < 4; ++nf)
                    acc[mf][nf] = __builtin_amdgcn_mfma_f32_16x16x32_f16(a[mf], b[nf], acc[mf][nf], 0, 0, 0);
        }
    };

    auto epilogue = [&](f32x4 (&acc)[4][4], const float (&bj)[4], _Float16* hout, bool first) {
        _Float16* hsm = &lds[0][0][0];
        const int lc = wn * 16 + lrow;
        #pragma unroll
        for (int mf = 0; mf < 4; ++mf)
            #pragma unroll
            for (int r = 0; r < 4; ++r) {
                int lr = wm * 64 + mf * 16 + (lane >> 4) * 4 + r;
                float gi = acc[mf][0][r] + bj[0];
                float gf = acc[mf][1][r] + bj[1];
                float gg = acc[mf][2][r] + bj[2];
                float go = acc[mf][3][r] + bj[3];
                float cold = first ? 0.0f : creg[mf][r];
                float cn = sigm(gf) * cold + sigm(gi) * tanh_fast(gg);
                creg[mf][r] = cn;
                hsm[lr * PAD_H + lc] = (_Float16)(sigm(go) * tanh_fast(cn));
            }
        __syncthreads();
        int rr = tid >> 3, k = tid & 7;
        #pragma unroll
        for (int q = 0; q < 4; ++q) {
            int r = rr + q * 32;
            unsigned long long v = *(const unsigned long long*)&hsm[r * PAD_H + k * 4];
            unsigned long long* dst =
                (unsigned long long*)(hout + (size_t)(m0 + r) * H_SZ + j0) + k;
            __hip_atomic_store(dst, v, __ATOMIC_RELAXED, __HIP_MEMORY_SCOPE_AGENT);
        }
    };

    // ================= phase A: encoder step 0 (x only, 4 tiles) =================
    {
        f32x4 acc[4][4] = {};
        #pragma unroll
        for (int q = 0; q < 4; ++q) { GLDS(xQ[q], &lds[0][0][ldsQ[q]]); GLDS(wEncQ[q], &lds[0][1][ldsQ[q]]); }
        #pragma unroll
        for (int it = 0; it < 4; ++it) {
            if (it < 3) {
                #pragma unroll
                for (int q = 0; q < 4; ++q) {
                    GLDS(xQ[q] + (it + 1) * 64, &lds[(it + 1) & 1][0][ldsQ[q]]);
                    GLDS(wEncQ[q] + (it + 1) * 64, &lds[(it + 1) & 1][1][ldsQ[q]]);
                }
                asm volatile("s_waitcnt vmcnt(8)" ::: "memory");
            } else {
                asm volatile("s_waitcnt vmcnt(0)" ::: "memory");
            }
            __builtin_amdgcn_s_barrier(); MEMFENCE;
            compute(it & 1, acc);
            MEMFENCE; __builtin_amdgcn_s_barrier(); MEMFENCE;
        }
        epilogue(acc, ebj, henc, true);
        arrive();
    }

    // ================= phase B: encoder steps 1..49 (12 tiles) =================
    for (int s = 1; s < S_SZ; ++s) {
        const size_t xoff = (size_t)s * B_SZ * I_SZ;
        const _Float16* hin = henc + (size_t)(s - 1) * BH;
        _Float16* hout = (s == S_SZ - 1) ? hseq : henc + (size_t)s * BH;
        f32x4 acc[4][4] = {};
        #pragma unroll
        for (int q = 0; q < 4; ++q) { GLDS(xQ[q] + xoff, &lds[0][0][ldsQ[q]]); GLDS(wEncQ[q], &lds[0][1][ldsQ[q]]); }
        #pragma unroll
        for (int it = 0; it < 12; ++it) {
            if (it < 11) {
                if (it == 3) wait_group((unsigned)s * 16u);
                #pragma unroll
                for (int q = 0; q < 4; ++q) {
                    if (it + 1 < 4) GLDS(xQ[q] + xoff + (it + 1) * 64, &lds[(it + 1) & 1][0][ldsQ[q]]);
                    else            GLDS(hin + aOffQ[q] + (it - 3) * 64, &lds[(it + 1) & 1][0][ldsQ[q]]);
                    GLDS(wEncQ[q] + (it + 1) * 64, &lds[(it + 1) & 1][1][ldsQ[q]]);
                }
                asm volatile("s_waitcnt vmcnt(8)" ::: "memory");
            } else {
                asm volatile("s_waitcnt vmcnt(0)" ::: "memory");
            }
            __builtin_amdgcn_s_barrier(); MEMFENCE;
            compute(it & 1, acc);
            MEMFENCE; __builtin_amdgcn_s_barrier(); MEMFENCE;
        }
        epilogue(acc, ebj, hout, false);
        arrive();
    }

    // ================= phase C: decoder steps 0..19 (8 tiles) =================
    for (int t = 0; t < T_SZ; ++t) {
        const _Float16* hin = hseq + (size_t)t * BH;
        _Float16* hout = hseq + (size_t)(t + 1) * BH;
        const _Float16* wq[4];
        float bj[4];
        #pragma unroll
        for (int q = 0; q < 4; ++q) wq[q] = t ? wDQ[q] : wD0Q[q];
        #pragma unroll
        for (int nf = 0; nf < 4; ++nf) bj[nf] = t ? bdj[nf] : dbj[nf];

        wait_group((unsigned)(S_SZ + t) * 16u);
        f32x4 acc[4][4] = {};
        #pragma unroll
        for (int q = 0; q < 4; ++q) { GLDS(hin + aOffQ[q], &lds[0][0][ldsQ[q]]); GLDS(wq[q], &lds[0][1][ldsQ[q]]); }
        #pragma unroll
        for (int it = 0; it < 8; ++it) {
            if (it < 7) {
                #pragma unroll
                for (int q = 0; q < 4; ++q) {
                    GLDS(hin + aOffQ[q] + (it + 1) * 64, &lds[(it + 1) & 1][0][ldsQ[q]]);
                    GLDS(wq[q] + (it + 1) * 64, &lds[(it + 1) & 1][1][ldsQ[q]]);
                }
                asm volatile("s_waitcnt vmcnt(8)" ::: "memory");
            } else {
                asm volatile("s_waitcnt vmcnt(0)" ::: "memory");
            }
            __builtin_amdgcn_s_barrier(); MEMFENCE;
            compute(it & 1, acc);
            MEMFENCE; __builtin_amdgcn_s_barrier(); MEMFENCE;
        }
        epilogue(acc, bj, hout, false);
        if (t != T_SZ - 1) arrive();
    }
}

// ---------------- batched final FC over all decoder h's ----------------
__global__ __launch_bounds__(256) void k_fc(
    const _Float16* __restrict__ hseq1,  // [T][B][512]
    const _Float16* __restrict__ W,      // fcW fp16 [256][512]
    const float* __restrict__ bias,      // [256]
    float* __restrict__ out)
{
    __shared__ _Float16 Asm[128][PAD];
    __shared__ _Float16 Bsm[128][PAD];

    const int tid = threadIdx.x;
    const int m0 = blockIdx.x * 128;
    const int t  = blockIdx.y;
    const int n0 = blockIdx.z * 128;
    const int wv = tid >> 6, lane = tid & 63, lrow = lane & 15, lk = (lane >> 4) * 8;
    const int wm = wv >> 1, wn = wv & 1;

    f32x4 acc[4][4] = {};

    const int srow = tid >> 3, skc = (tid & 7) * 8;
    const _Float16* A = hseq1 + (size_t)t * BH;

    for (int k0 = 0; k0 < H_SZ; k0 += 64) {
        __syncthreads();
        #pragma unroll
        for (int q = 0; q < 4; ++q) {
            int r = srow + q * 32;
            *(half8*)&Asm[r][skc] = *(const half8*)(A + (size_t)(m0 + r) * H_SZ + k0 + skc);
        }
        #pragma unroll
        for (int q = 0; q < 4; ++q) {
            int rr = srow + q * 32;
            *(half8*)&Bsm[rr][skc] = *(const half8*)(W + (size_t)(n0 + rr) * H_SZ + k0 + skc);
        }
        __syncthreads();
        #pragma unroll
        for (int kc = 0; kc < 64; kc += 32) {
            half8 a[4], b[4];
            #pragma unroll
            for (int mf = 0; mf < 4; ++mf) a[mf] = *(const half8*)&Asm[wm * 64 + mf * 16 + lrow][kc + lk];
            #pragma unroll
            for (int nf = 0; nf < 4; ++nf) b[nf] = *(const half8*)&Bsm[wn * 64 + nf * 16 + lrow][kc + lk];
            #pragma unroll
            for (int mf = 0; mf < 4; ++mf)
                #pragma unroll
                for (int nf = 0; nf < 4; ++nf)
                    acc[mf][nf] = __builtin_amdgcn_mfma_f32_16x16x32_f16(a[mf], b[nf], acc[mf][nf], 0, 0, 0);
        }
    }

    #pragma unroll
    for (int mf = 0; mf < 4; ++mf)
        #pragma unroll
        for (int nf = 0; nf < 4; ++nf) {
            int o = n0 + wn * 64 + nf * 16 + lrow;
            float bv = bias[o];
            #pragma unroll
            for (int r = 0; r < 4; ++r) {
                int m = m0 + wm * 64 + mf * 16 + (lane >> 4) * 4 + r;
                out[(size_t)m * (T_SZ * O_SZ) + (size_t)t * O_SZ + o] = acc[mf][nf][r] + bv;
            }
        }
}

extern "C" void kernel_launch(void* const* d_in, const int* in_sizes, int n_in,
                              void* d_out, int out_size, void* d_ws, size_t ws_size,
                              hipStream_t stream) {
    (void)in_sizes; (void)n_in; (void)out_size; (void)ws_size;

    const float* x    = (const float*)d_in[0];
    const float* eWih = (const float*)d_in[1];
    const float* eWhh = (const float*)d_in[2];
    const float* ebih = (const float*)d_in[3];
    const float* ebhh = (const float*)d_in[4];
    const float* dWih = (const float*)d_in[5];
    const float* dWhh = (const float*)d_in[6];
    const float* dbih = (const float*)d_in[7];
    const float* dbhh = (const float*)d_in[8];
    const float* fcW  = (const float*)d_in[9];
    const float* fcb  = (const float*)d_in[10];
    float* out = (float*)d_out;
    char* ws = (char*)d_ws;

    size_t off = 0;
    auto alloc = [&](size_t bytes) -> void* {
        void* p = ws + off;
        off += (bytes + 255) & ~(size_t)255;
        return p;
    };
    _Float16* xT     = (_Float16*)alloc((size_t)S_SZ * B_SZ * I_SZ * 2);
    _Float16* Wenc   = (_Float16*)alloc((size_t)G4H * (I_SZ + H_SZ) * 2);
    _Float16* dWhh_h = (_Float16*)alloc((size_t)G4H * H_SZ * 2);
    _Float16* Wd     = (_Float16*)alloc((size_t)G4H * H_SZ * 2);
    _Float16* fcW_h  = (_Float16*)alloc((size_t)O_SZ * H_SZ * 2);
    float*    eb     = (float*)alloc(G4H * 4);
    float*    db     = (float*)alloc(G4H * 4);
    float*    bd     = (float*)alloc(G4H * 4);
    _Float16* henc   = (_Float16*)alloc((size_t)(S_SZ - 1) * BH * 2);   // 49 slabs
    _Float16* hseq   = (_Float16*)alloc((size_t)(T_SZ + 1) * BH * 2);   // 21 slabs
    unsigned* bar    = (unsigned*)alloc(32 * 16 * 4);

    const int nWhh = G4H * H_SZ;
    const int nFc  = O_SZ * H_SZ;
    const size_t nX = (size_t)B_SZ * S_SZ * I_SZ;

    k_zeroN<<<2, 256, 0, stream>>>(bar, 32 * 16);
    k_cvt_x<<<(int)(nX / 8 / 256), 256, 0, stream>>>(x, xT);
    k_wenc<<<(G4H * 768) / 256, 256, 0, stream>>>(eWih, eWhh, Wenc);
    k_cvt<<<(nWhh + 255) / 256, 256, 0, stream>>>(dWhh, dWhh_h, nWhh);
    k_cvt<<<(nFc + 255) / 256, 256, 0, stream>>>(fcW, fcW_h, nFc);
    k_bias_combine<<<8, 256, 0, stream>>>(ebih, ebhh, eb, G4H);
    k_bias_combine<<<8, 256, 0, stream>>>(dbih, dbhh, db, G4H);
    k_wd<<<256, 256, 0, stream>>>(dWhh, dWih, fcW, Wd);
    k_bd<<<8, 256, 0, stream>>>(dWih, fcb, db, bd);

    k_lstm_all<<<NB, 256, 0, stream>>>(xT, Wenc, dWhh_h, Wd, eb, db, bd,
                                       henc, hseq, bar);

    k_fc<<<dim3(B_SZ / 128, T_SZ, O_SZ / 128), 256, 0, stream>>>(
        hseq + BH, fcW_h, fcb, out);
}